// Round 2
// baseline (2094.260 us; speedup 1.0000x reference)
//
#include <hip/hip_runtime.h>

#define NN   10000
#define NE   160000
#define DIM  240
#define LATD 128
#define TE   8     // edges per block (edge kernel)
#define NPB  4     // nodes per block (node kernel)

__device__ __forceinline__ float sigf(float x) { return 1.0f / (1.0f + __expf(-x)); }

// ---------------------------------------------------------------------------
// Edge kernel: per-edge SO(2)/SO(3) message construction + atomic segment-sum
// ---------------------------------------------------------------------------
__global__ __launch_bounds__(256) void edge_kernel(
    const float* __restrict__ nf, const float* __restrict__ ef,
    const float* __restrict__ latg, const float* __restrict__ D1g, const float* __restrict__ D2g,
    const float* __restrict__ W0, const float* __restrict__ W1, const float* __restrict__ W2,
    const float* __restrict__ Ws, const float* __restrict__ We,
    const float* __restrict__ pW0, const float* __restrict__ pb0,
    const float* __restrict__ pW1, const float* __restrict__ pW2,
    const int* __restrict__ srcg, float* agg)
{
    // edge-transposed layouts ([.. ][el]) so a float4 LDS read spans 4 edges
    __shared__ __align__(16) float latf[128 * TE];     // [k*TE+el]
    __shared__ __align__(16) float sinf_[128 * TE];    // [k*TE+el]
    __shared__ __align__(16) float v1rt[3 * 64 * TE];  // [(i*64+c)*TE+el]
    __shared__ __align__(16) float v2rt[5 * 32 * TE];  // [(i*32+c)*TE+el]
    __shared__ float d1s[TE][9];
    __shared__ float d2s[TE][25];
    __shared__ float scs[TE][160];
    __shared__ float wvs[TE][112];
    __shared__ float smr[TE][112];
    __shared__ __align__(16) float sactf[64 * TE];     // [o*TE+el]
    __shared__ float gts[TE][48];
    __shared__ float v1t[TE][3][32];
    __shared__ float v2t[TE][5][16];
    __shared__ __align__(16) float v1gt[3 * 32 * TE];  // [(j*32+o)*TE+el]
    __shared__ __align__(16) float v2gt[5 * 16 * TE];  // [(j*16+o)*TE+el]
    __shared__ int srcs[TE];

    const int t  = threadIdx.x;
    const int e0 = blockIdx.x * TE;

    if (t < TE) srcs[t] = srcg[e0 + t];
    __syncthreads();

    // ---- phase 1: stage latents, s_in, D1, D2 ----
    for (int idx = t; idx < TE * 128; idx += 256) {
        int el = idx >> 7, k = idx & 127;
        latf[k * TE + el]  = latg[(e0 + el) * LATD + k];
        sinf_[k * TE + el] = (k < 64) ? nf[srcs[el] * DIM + k]
                                      : ef[(e0 + el) * DIM + (k - 64)];
    }
    for (int idx = t; idx < TE * 9; idx += 256) {
        int el = idx / 9, r = idx - el * 9;
        d1s[el][r] = D1g[(e0 + el) * 9 + r];
    }
    for (int idx = t; idx < TE * 25; idx += 256) {
        int el = idx / 25, r = idx - el * 25;
        d2s[el][r] = D2g[(e0 + el) * 25 + r];
    }
    __syncthreads();

    // ---- phase 1b: rotate v1,v2 into frame (v_r = D v_in) ----
    for (int idx = t; idx < TE * 192 + TE * 160; idx += 256) {
        if (idx < TE * 192) {
            int el = idx / 192, r = idx - el * 192;
            int i = r >> 6, c = r & 63;
            const float* v = (c < 32) ? (nf + srcs[el] * DIM + 64 + c * 3)
                                      : (ef + (e0 + el) * DIM + 64 + (c - 32) * 3);
            v1rt[(i * 64 + c) * TE + el] =
                d1s[el][i * 3 + 0] * v[0] + d1s[el][i * 3 + 1] * v[1] + d1s[el][i * 3 + 2] * v[2];
        } else {
            int idx2 = idx - TE * 192;
            int el = idx2 / 160, r = idx2 - el * 160;
            int i = r >> 5, c = r & 31;
            const float* v = (c < 16) ? (nf + srcs[el] * DIM + 160 + c * 5)
                                      : (ef + (e0 + el) * DIM + 160 + (c - 16) * 5);
            float a = 0.f;
            #pragma unroll
            for (int j = 0; j < 5; j++) a += d2s[el][i * 5 + j] * v[j];
            v2rt[(i * 32 + c) * TE + el] = a;
        }
    }

    // ---- phase 2: sc = lat@Ws (160), w = lat@We (112), smr = s_in@W0 (112) ----
    // 4-edge register blocking: one weight load feeds 4 FMAs.
    for (int idx = t; idx < (TE / 4) * 384; idx += 256) {
        int g = idx / 384, o = idx - g * 384;
        float ax = 0.f, ay = 0.f, az = 0.f, aw = 0.f;
        if (o < 160) {
            const float* wp = Ws + o;
            #pragma unroll 4
            for (int k = 0; k < 128; k++) {
                float w = wp[k * 160];
                float4 a = *(const float4*)&latf[k * TE + 4 * g];
                ax += a.x * w; ay += a.y * w; az += a.z * w; aw += a.w * w;
            }
            scs[4 * g + 0][o] = ax; scs[4 * g + 1][o] = ay;
            scs[4 * g + 2][o] = az; scs[4 * g + 3][o] = aw;
        } else if (o < 272) {
            int oo = o - 160;
            const float* wp = We + oo;
            #pragma unroll 4
            for (int k = 0; k < 128; k++) {
                float w = wp[k * 112];
                float4 a = *(const float4*)&latf[k * TE + 4 * g];
                ax += a.x * w; ay += a.y * w; az += a.z * w; aw += a.w * w;
            }
            wvs[4 * g + 0][oo] = ax; wvs[4 * g + 1][oo] = ay;
            wvs[4 * g + 2][oo] = az; wvs[4 * g + 3][oo] = aw;
        } else {
            int oo = o - 272;
            const float* wp = W0 + oo;
            #pragma unroll 4
            for (int k = 0; k < 128; k++) {
                float w = wp[k * 112];
                float4 a = *(const float4*)&sinf_[k * TE + 4 * g];
                ax += a.x * w; ay += a.y * w; az += a.z * w; aw += a.w * w;
            }
            smr[4 * g + 0][oo] = ax; smr[4 * g + 1][oo] = ay;
            smr[4 * g + 2][oo] = az; smr[4 * g + 3][oo] = aw;
        }
    }
    __syncthreads();

    // ---- phase 3: activations/gates + v1_m, v2_m (scaled by sc) ----
    {
        const int R1 = (TE / 4) * 32;        // v1: 64 heavy items
        const int R2 = R1 + (TE / 4) * 16;   // v2: 32 heavy items
        const int R3 = R2 + TE * 112;        // sm: 896 light items
        for (int idx = t; idx < R3; idx += 256) {
            if (idx < R1) {
                int g = idx >> 5, o = idx & 31;
                float a[3][4] = {{0.f}};
                #pragma unroll 2
                for (int c = 0; c < 64; c++) {
                    float w = W1[c * 32 + o];
                    #pragma unroll
                    for (int i = 0; i < 3; i++) {
                        float4 x = *(const float4*)&v1rt[(i * 64 + c) * TE + 4 * g];
                        a[i][0] += x.x * w; a[i][1] += x.y * w;
                        a[i][2] += x.z * w; a[i][3] += x.w * w;
                    }
                }
                #pragma unroll
                for (int e = 0; e < 4; e++) {
                    int el = 4 * g + e;
                    float s = scs[el][112 + o];
                    #pragma unroll
                    for (int i = 0; i < 3; i++) v1t[el][i][o] = a[i][e] * s;
                }
            } else if (idx < R2) {
                int idx2 = idx - R1;
                int g = idx2 >> 4, o = idx2 & 15;
                float a[5][4] = {{0.f}};
                #pragma unroll 2
                for (int c = 0; c < 32; c++) {
                    float w = W2[c * 16 + o];
                    #pragma unroll
                    for (int i = 0; i < 5; i++) {
                        float4 x = *(const float4*)&v2rt[(i * 32 + c) * TE + 4 * g];
                        a[i][0] += x.x * w; a[i][1] += x.y * w;
                        a[i][2] += x.z * w; a[i][3] += x.w * w;
                    }
                }
                #pragma unroll
                for (int e = 0; e < 4; e++) {
                    int el = 4 * g + e;
                    float s = scs[el][144 + o];
                    #pragma unroll
                    for (int i = 0; i < 5; i++) v2t[el][i][o] = a[i][e] * s;
                }
            } else {
                int idx2 = idx - R2;
                int el = idx2 / 112, o = idx2 - el * 112;
                float v = smr[el][o] * scs[el][o];
                if (o < 64) sactf[o * TE + el] = v * sigf(v);   // silu
                else        gts[el][o - 64]   = sigf(v);        // gate
            }
        }
    }
    __syncthreads();

    // ---- phase 4: rotate back (D v_m) + apply gates ----
    for (int idx = t; idx < TE * 96 + TE * 80; idx += 256) {
        if (idx < TE * 96) {
            int el = idx / 96, r = idx - el * 96;
            int j = r >> 5, o = r & 31;
            float a = d1s[el][j * 3 + 0] * v1t[el][0][o] +
                      d1s[el][j * 3 + 1] * v1t[el][1][o] +
                      d1s[el][j * 3 + 2] * v1t[el][2][o];
            v1gt[(j * 32 + o) * TE + el] = a * gts[el][o];
        } else {
            int idx2 = idx - TE * 96;
            int el = idx2 / 80, r = idx2 - el * 80;
            int j = r >> 4, o = r & 15;
            float a = 0.f;
            #pragma unroll
            for (int i = 0; i < 5; i++) a += d2s[el][j * 5 + i] * v2t[el][i][o];
            v2gt[(j * 16 + o) * TE + el] = a * gts[el][32 + o];
        }
    }
    __syncthreads();

    // ---- phase 5: post matmuls * env weight, atomic scatter to agg ----
    for (int idx = t; idx < (TE / 4) * 240; idx += 256) {
        int g = idx / 240, d = idx - g * 240;
        float a[4] = {0.f, 0.f, 0.f, 0.f};
        if (d < 64) {
            #pragma unroll 2
            for (int c = 0; c < 64; c++) {
                float w = pW0[c * 64 + d];
                float4 x = *(const float4*)&sactf[c * TE + 4 * g];
                a[0] += x.x * w; a[1] += x.y * w; a[2] += x.z * w; a[3] += x.w * w;
            }
            float b = pb0[d];
            #pragma unroll
            for (int e = 0; e < 4; e++) {
                int el = 4 * g + e;
                float val = (a[e] + b) * wvs[el][d];
                atomicAdd(&agg[srcs[el] * DIM + d], val);
            }
        } else if (d < 160) {
            int dd = d - 64, o = dd / 3, j = dd - o * 3;
            #pragma unroll 2
            for (int c = 0; c < 32; c++) {
                float w = pW1[c * 32 + o];
                float4 x = *(const float4*)&v1gt[(j * 32 + c) * TE + 4 * g];
                a[0] += x.x * w; a[1] += x.y * w; a[2] += x.z * w; a[3] += x.w * w;
            }
            #pragma unroll
            for (int e = 0; e < 4; e++) {
                int el = 4 * g + e;
                float val = a[e] * wvs[el][64 + o];
                atomicAdd(&agg[srcs[el] * DIM + d], val);
            }
        } else {
            int dd = d - 160, o = dd / 5, j = dd - o * 5;
            #pragma unroll 2
            for (int c = 0; c < 16; c++) {
                float w = pW2[c * 16 + o];
                float4 x = *(const float4*)&v2gt[(j * 16 + c) * TE + 4 * g];
                a[0] += x.x * w; a[1] += x.y * w; a[2] += x.z * w; a[3] += x.w * w;
            }
            #pragma unroll
            for (int e = 0; e < 4; e++) {
                int el = 4 * g + e;
                float val = a[e] * wvs[el][96 + o];
                atomicAdd(&agg[srcs[el] * DIM + d], val);
            }
        }
    }
}

// ---------------------------------------------------------------------------
// Node kernel: coeffs MLP, message-coupling MLP + LN, residual, one-hot gain.
// Reads agg from the out0 region and overwrites it with the final output.
// ---------------------------------------------------------------------------
__global__ __launch_bounds__(256) void node_kernel(
    const float* __restrict__ nf, const float* __restrict__ mcplg,
    const float* __restrict__ ohg,
    const float* __restrict__ cW1, const float* __restrict__ cb1,
    const float* __restrict__ cW2, const float* __restrict__ cb2,
    const float* __restrict__ gsW, const float* __restrict__ gsb,
    const float* __restrict__ mW1, const float* __restrict__ mb1,
    const float* __restrict__ mW2, const float* __restrict__ mb2,
    const float* __restrict__ lng, const float* __restrict__ lnb,
    const float* __restrict__ rW0, const float* __restrict__ rb0,
    const float* __restrict__ rW1, const float* __restrict__ rW2,
    const float* __restrict__ w0g, const float* __restrict__ w1g, const float* __restrict__ w2g,
    float* out0, float* out1)
{
    __shared__ float mcp[NPB][128];
    __shared__ float ohv[NPB][96];
    __shared__ float nsr[NPB][240];
    __shared__ float anew[NPB][240];
    __shared__ float t1[NPB][128];
    __shared__ float cfs[NPB][112];
    __shared__ float scl[NPB][128];
    __shared__ float t2[NPB][128];
    __shared__ float mcn[NPB][128];
    __shared__ float gv[NPB][112];

    const int t  = threadIdx.x;
    const int n0 = blockIdx.x * NPB;

    for (int idx = t; idx < NPB * 128; idx += 256) {
        int n = idx >> 7, k = idx & 127;
        mcp[n][k] = mcplg[(n0 + n) * 128 + k];
    }
    for (int idx = t; idx < NPB * 95; idx += 256) {
        int n = idx / 95, k = idx - n * 95;
        ohv[n][k] = ohg[(n0 + n) * 95 + k];
    }
    for (int idx = t; idx < NPB * 240; idx += 256) {
        int n = idx / 240, k = idx - n * 240;
        nsr[n][k]  = nf[(n0 + n) * DIM + k];
        anew[n][k] = out0[(n0 + n) * DIM + k];   // agg (atomic sums)
    }
    __syncthreads();

    // t1 = silu(mcp @ cW1 + cb1)
    for (int idx = t; idx < NPB * 128; idx += 256) {
        int n = idx >> 7, o = idx & 127;
        float acc = cb1[o];
        #pragma unroll 4
        for (int k = 0; k < 128; k++) acc += mcp[n][k] * cW1[k * 128 + o];
        t1[n][o] = acc * sigf(acc);
    }
    __syncthreads();

    // coeffs = t1 @ cW2 + cb2
    for (int idx = t; idx < NPB * 112; idx += 256) {
        int n = idx / 112, o = idx - n * 112;
        float acc = cb2[o];
        #pragma unroll 4
        for (int k = 0; k < 128; k++) acc += t1[n][k] * cW2[k * 112 + o];
        cfs[n][o] = acc;
    }
    __syncthreads();

    // new_nf = agg * 0.25 * coeffs[SCALE_IDX]
    for (int idx = t; idx < NPB * 240; idx += 256) {
        int n = idx / 240, d = idx - n * 240;
        int ch = (d < 64) ? d : (d < 160 ? 64 + (d - 64) / 3 : 96 + (d - 160) / 5);
        anew[n][d] = anew[n][d] * 0.25f * cfs[n][ch];
    }
    __syncthreads();

    // scal = new_nf[:,:64] @ gsW + gsb
    for (int idx = t; idx < NPB * 128; idx += 256) {
        int n = idx >> 7, o = idx & 127;
        float acc = gsb[o];
        #pragma unroll 4
        for (int c = 0; c < 64; c++) acc += anew[n][c] * gsW[c * 128 + o];
        scl[n][o] = acc;
    }
    __syncthreads();

    // t2 = silu([scal, mcp] @ mW1 + mb1)
    for (int idx = t; idx < NPB * 128; idx += 256) {
        int n = idx >> 7, o = idx & 127;
        float acc = mb1[o];
        #pragma unroll 4
        for (int k = 0; k < 128; k++) acc += scl[n][k] * mW1[k * 128 + o];
        #pragma unroll 4
        for (int k = 0; k < 128; k++) acc += mcp[n][k] * mW1[(128 + k) * 128 + o];
        t2[n][o] = acc * sigf(acc);
    }
    __syncthreads();

    // mcn = mcp + t2 @ mW2 + mb2
    for (int idx = t; idx < NPB * 128; idx += 256) {
        int n = idx >> 7, o = idx & 127;
        float acc = mb2[o];
        #pragma unroll 4
        for (int k = 0; k < 128; k++) acc += t2[n][k] * mW2[k * 128 + o];
        mcn[n][o] = mcp[n][o] + acc;
    }
    __syncthreads();

    // LayerNorm: wave w handles node w (64 lanes, 2 elems each)
    {
        int w = t >> 6, l = t & 63;
        float a = mcn[w][l], b = mcn[w][64 + l];
        float s = a + b, ss = a * a + b * b;
        #pragma unroll
        for (int off = 32; off > 0; off >>= 1) {
            s  += __shfl_down(s,  off, 64);
            ss += __shfl_down(ss, off, 64);
        }
        s  = __shfl(s, 0, 64);
        ss = __shfl(ss, 0, 64);
        float mu   = s * (1.f / 128.f);
        float var  = ss * (1.f / 128.f) - mu * mu;
        float rstd = rsqrtf(var + 1e-5f);
        out1[(n0 + w) * 128 + l]      = (a - mu) * rstd * lng[l]      + lnb[l];
        out1[(n0 + w) * 128 + 64 + l] = (b - mu) * rstd * lng[64 + l] + lnb[64 + l];
    }

    // one-hot gains
    for (int idx = t; idx < NPB * 112; idx += 256) {
        int n = idx / 112, o = idx - n * 112;
        const float* wp;
        if (o < 64)      wp = w0g + o * 95;
        else if (o < 96) wp = w1g + (o - 64) * 95;
        else             wp = w2g + (o - 96) * 95;
        float acc = 0.f;
        #pragma unroll 5
        for (int k = 0; k < 95; k++) acc += ohv[n][k] * wp[k];
        gv[n][o] = acc * 0.10259783521f;   // 1/sqrt(95)
    }
    __syncthreads();

    // residual + combine + one-hot gain, write out0
    const float c_new = 0.4472135955f;   // 0.5 * rsqrt(1.25)
    const float c_old = 0.8944271910f;   // rsqrt(1.25)
    for (int idx = t; idx < NPB * 240; idx += 256) {
        int n = idx / 240, d = idx - n * 240;
        float res, g;
        if (d < 64) {
            float acc = rb0[d];
            #pragma unroll 4
            for (int c = 0; c < 64; c++) acc += nsr[n][c] * rW0[c * 64 + d];
            res = acc; g = gv[n][d];
        } else if (d < 160) {
            int dd = d - 64, o = dd / 3, j = dd - o * 3;
            float acc = 0.f;
            #pragma unroll 4
            for (int c = 0; c < 32; c++) acc += nsr[n][64 + c * 3 + j] * rW1[c * 32 + o];
            res = acc; g = gv[n][64 + o];
        } else {
            int dd = d - 160, o = dd / 5, j = dd - o * 5;
            float acc = 0.f;
            #pragma unroll 4
            for (int c = 0; c < 16; c++) acc += nsr[n][160 + c * 5 + j] * rW2[c * 16 + o];
            res = acc; g = gv[n][96 + o];
        }
        float v = c_new * anew[n][d] + c_old * res;
        out0[(n0 + n) * DIM + d] = v * (1.f + g);
    }
}

extern "C" void kernel_launch(void* const* d_in, const int* in_sizes, int n_in,
                              void* d_out, int out_size, void* d_ws, size_t ws_size,
                              hipStream_t stream) {
    const float* nf      = (const float*)d_in[0];
    const float* ef      = (const float*)d_in[1];
    const float* lat     = (const float*)d_in[2];
    const float* mcpl    = (const float*)d_in[3];
    const float* ohot    = (const float*)d_in[4];
    const float* D1      = (const float*)d_in[5];
    const float* D2      = (const float*)d_in[6];
    const float* so2_W0  = (const float*)d_in[7];
    const float* so2_W1  = (const float*)d_in[8];
    const float* so2_W2  = (const float*)d_in[9];
    const float* so2_Ws  = (const float*)d_in[10];
    const float* env_W   = (const float*)d_in[11];
    const float* post_W0 = (const float*)d_in[12];
    const float* post_b0 = (const float*)d_in[13];
    const float* post_W1 = (const float*)d_in[14];
    const float* post_W2 = (const float*)d_in[15];
    const float* res_W0  = (const float*)d_in[16];
    const float* res_b0  = (const float*)d_in[17];
    const float* res_W1  = (const float*)d_in[18];
    const float* res_W2  = (const float*)d_in[19];
    const float* cpl_W1  = (const float*)d_in[20];
    const float* cpl_b1  = (const float*)d_in[21];
    const float* cpl_W2  = (const float*)d_in[22];
    const float* cpl_b2  = (const float*)d_in[23];
    const float* gs_W    = (const float*)d_in[24];
    const float* gs_b    = (const float*)d_in[25];
    const float* msg_W1  = (const float*)d_in[26];
    const float* msg_b1  = (const float*)d_in[27];
    const float* msg_W2  = (const float*)d_in[28];
    const float* msg_b2  = (const float*)d_in[29];
    const float* ln_g    = (const float*)d_in[30];
    const float* ln_b    = (const float*)d_in[31];
    const float* oh_w0   = (const float*)d_in[32];
    const float* oh_w1   = (const float*)d_in[33];
    const float* oh_w2   = (const float*)d_in[34];
    const int*   eidx    = (const int*)d_in[35];   // (2,E); row 0 = src

    float* out0 = (float*)d_out;            // N*DIM, doubles as agg buffer
    float* out1 = (float*)d_out + (size_t)NN * DIM;  // N*CPL

    (void)hipMemsetAsync(out0, 0, (size_t)NN * DIM * sizeof(float), stream);

    edge_kernel<<<NE / TE, 256, 0, stream>>>(
        nf, ef, lat, D1, D2, so2_W0, so2_W1, so2_W2, so2_Ws, env_W,
        post_W0, post_b0, post_W1, post_W2, eidx, out0);

    node_kernel<<<NN / NPB, 256, 0, stream>>>(
        nf, mcpl, ohot, cpl_W1, cpl_b1, cpl_W2, cpl_b2, gs_W, gs_b,
        msg_W1, msg_b1, msg_W2, msg_b2, ln_g, ln_b,
        res_W0, res_b0, res_W1, res_W2, oh_w0, oh_w1, oh_w2, out0, out1);
}

// Round 3
// 1023.999 us; speedup vs baseline: 2.0452x; 2.0452x over previous
//
#include <hip/hip_runtime.h>

#define NN   10000
#define NE   160000
#define DIM  240
#define EB   16    // edges per block (edge kernel)
#define NPB  4     // nodes per block (node kernel)

typedef __bf16 bf16x8 __attribute__((ext_vector_type(8)));
typedef float  f32x4  __attribute__((ext_vector_type(4)));

__device__ __forceinline__ float sigf(float x) { return 1.0f / (1.0f + __expf(-x)); }

// -------- workspace layout (bf16 elements) : weight B-fragments --------
// B-fragment convention for mfma_f32_16x16x32_bf16:
//   lane l holds B[k = (l>>4)*8 + j][n = l&15], j=0..7, per (n_tile, k_step)
// linear index = ((nt*KS + ks)*64 + lane)*8 + j
#define OFF_WB1 0        // [Ws|We]: N=272 (17 nt), K=128 (4 ks): 34816 elems
#define OFF_WB2 34816    // W0:      N=112 (7 nt),  K=128 (4 ks): 14336
#define OFF_W1  49152    // so2_W1:  N=32 (2 nt),   K=64  (2 ks): 2048
#define OFF_W2  51200    // so2_W2:  N=16 (1 nt),   K=32  (1 ks): 512
#define OFF_PW0 51712    // post_W0: N=64 (4 nt),   K=64  (2 ks): 4096
#define OFF_PW1 55808    // post_W1: N=32 (2 nt),   K=32  (1 ks): 1024
#define OFF_PW2 56832    // post_W2: N=16 (1 nt),   K=16 pad 32:  512

__global__ __launch_bounds__(256) void prep_kernel(
    const float* __restrict__ Ws, const float* __restrict__ We, const float* __restrict__ W0,
    const float* __restrict__ W1, const float* __restrict__ W2,
    const float* __restrict__ pW0, const float* __restrict__ pW1, const float* __restrict__ pW2,
    __bf16* __restrict__ wsb)
{
    int tid = blockIdx.x * 256 + threadIdx.x;
    int stride = gridDim.x * 256;
    for (int idx = tid; idx < 17*4*512; idx += stride) {
        int j = idx & 7, lane = (idx >> 3) & 63, ks = (idx >> 9) & 3, nt = idx >> 11;
        int k = ks*32 + (lane >> 4)*8 + j, n = nt*16 + (lane & 15);
        float v = (n < 160) ? Ws[k*160 + n] : We[k*112 + (n - 160)];
        wsb[OFF_WB1 + idx] = (__bf16)v;
    }
    for (int idx = tid; idx < 7*4*512; idx += stride) {
        int j = idx & 7, lane = (idx >> 3) & 63, ks = (idx >> 9) & 3, nt = idx >> 11;
        int k = ks*32 + (lane >> 4)*8 + j, n = nt*16 + (lane & 15);
        wsb[OFF_WB2 + idx] = (__bf16)W0[k*112 + n];
    }
    for (int idx = tid; idx < 2*2*512; idx += stride) {
        int j = idx & 7, lane = (idx >> 3) & 63, ks = (idx >> 9) & 1, nt = idx >> 10;
        int k = ks*32 + (lane >> 4)*8 + j, n = nt*16 + (lane & 15);
        wsb[OFF_W1 + idx] = (__bf16)W1[k*32 + n];
    }
    for (int idx = tid; idx < 512; idx += stride) {
        int j = idx & 7, lane = (idx >> 3) & 63;
        int k = (lane >> 4)*8 + j, n = lane & 15;
        wsb[OFF_W2 + idx] = (__bf16)W2[k*16 + n];
    }
    for (int idx = tid; idx < 4*2*512; idx += stride) {
        int j = idx & 7, lane = (idx >> 3) & 63, ks = (idx >> 9) & 1, nt = idx >> 10;
        int k = ks*32 + (lane >> 4)*8 + j, n = nt*16 + (lane & 15);
        wsb[OFF_PW0 + idx] = (__bf16)pW0[k*64 + n];
    }
    for (int idx = tid; idx < 2*512; idx += stride) {
        int j = idx & 7, lane = (idx >> 3) & 63, nt = idx >> 9;
        int k = (lane >> 4)*8 + j, n = nt*16 + (lane & 15);
        wsb[OFF_PW1 + idx] = (__bf16)pW1[k*32 + n];
    }
    for (int idx = tid; idx < 512; idx += stride) {
        int j = idx & 7, lane = (idx >> 3) & 63;
        int k = (lane >> 4)*8 + j, n = lane & 15;
        wsb[OFF_PW2 + idx] = (k < 16) ? (__bf16)pW2[k*16 + n] : (__bf16)0.0f;
    }
}

// ---------------------------------------------------------------------------
// Edge kernel (MFMA): 16 edges/block, 256 threads (4 waves).
// A-fragments in LDS in exact fragment order (lane-linear 16B chunks).
// ---------------------------------------------------------------------------
__global__ __launch_bounds__(256) void edge_mfma_kernel(
    const float* __restrict__ nf, const float* __restrict__ ef,
    const float* __restrict__ latg, const float* __restrict__ D1g, const float* __restrict__ D2g,
    const float* __restrict__ pb0, const int* __restrict__ srcg,
    const __bf16* __restrict__ wsb, float* agg)
{
    __shared__ __align__(16) unsigned char pool[61376];
    float*  Cb   = (float*)(pool + 0);       // [16][388]: 0..160 sc | 160..272 w | 272..384 smr
    float*  v1m  = (float*)(pool + 24832);   // [3][16][33]
    float*  v2m  = (float*)(pool + 31168);   // [5][16][17]
    float*  d1s  = (float*)(pool + 36608);   // [16*9]
    float*  d2s  = (float*)(pool + 37184);   // [16*25]
    float*  gts  = (float*)(pool + 38784);   // [16*48]
    int*    srcs = (int*)  (pool + 41856);   // [16]
    __bf16* aLat = (__bf16*)(pool + 41920);  // [4 ks][64][8]   (dead after GEMM1)
    __bf16* aSin = (__bf16*)(pool + 46016);  // [4 ks][64][8]   (dead after GEMM1)
    __bf16* aV1r = (__bf16*)(pool + 50112);  // [3][2 ks][64][8](dead after GEMM2)
    __bf16* aV2r = (__bf16*)(pool + 56256);  // [5][64][8]      (dead after GEMM2)
    __bf16* aSact= (__bf16*)(pool + 41920);  // alias over aLat   [2 ks][64][8]
    __bf16* aV1g = (__bf16*)(pool + 43968);  // alias             [3][64][8]
    __bf16* aV2g = (__bf16*)(pool + 47040);  // alias             [5][64][8]

    const int t    = threadIdx.x;
    const int wid  = t >> 6, lane = t & 63;
    const int e0   = blockIdx.x * EB;

    // ---- T0a: srcs + D matrices ----
    if (t < 16) srcs[t] = srcg[e0 + t];
    for (int idx = t; idx < 144; idx += 256) d1s[idx] = D1g[e0*9  + idx];
    for (int idx = t; idx < 400; idx += 256) d2s[idx] = D2g[e0*25 + idx];
    __syncthreads();

    // ---- T0b: stage A fragments (bf16, fragment order) ----
    {
        // aLat & aSin: thread t handles fragment chunk t = ks*64+lane
        int ks = t >> 6, l2 = t & 63, e = l2 & 15, q = l2 >> 4;
        int k0 = ks*32 + q*8;
        {
            const float4* p4 = (const float4*)(latg + (e0 + e)*128 + k0);
            float4 f0 = p4[0], f1 = p4[1];
            bf16x8 v;
            v[0]=(__bf16)f0.x; v[1]=(__bf16)f0.y; v[2]=(__bf16)f0.z; v[3]=(__bf16)f0.w;
            v[4]=(__bf16)f1.x; v[5]=(__bf16)f1.y; v[6]=(__bf16)f1.z; v[7]=(__bf16)f1.w;
            *(bf16x8*)(aLat + t*8) = v;
        }
        {
            const float* s2 = (k0 < 64) ? (nf + srcs[e]*240 + k0)
                                        : (ef + (e0 + e)*240 + (k0 - 64));
            const float4* p4 = (const float4*)s2;
            float4 f0 = p4[0], f1 = p4[1];
            bf16x8 v;
            v[0]=(__bf16)f0.x; v[1]=(__bf16)f0.y; v[2]=(__bf16)f0.z; v[3]=(__bf16)f0.w;
            v[4]=(__bf16)f1.x; v[5]=(__bf16)f1.y; v[6]=(__bf16)f1.z; v[7]=(__bf16)f1.w;
            *(bf16x8*)(aSin + t*8) = v;
        }
    }
    // aV1r: rotate v1_in into frame while staging (384 chunks)
    for (int idx = t; idx < 384; idx += 256) {
        int i = idx >> 7, rem = idx & 127, l2 = rem & 63;
        int ks = rem >> 6, e = l2 & 15, q = l2 >> 4;
        int c0 = ks*32 + q*8;
        float da = d1s[e*9 + i*3 + 0], db = d1s[e*9 + i*3 + 1], dc = d1s[e*9 + i*3 + 2];
        const float* base = (c0 < 32) ? (nf + srcs[e]*240 + 64 + c0*3)
                                      : (ef + (e0 + e)*240 + 64 + (c0 - 32)*3);
        bf16x8 v;
        #pragma unroll
        for (int j = 0; j < 8; j++) {
            const float* p = base + j*3;
            v[j] = (__bf16)(da*p[0] + db*p[1] + dc*p[2]);
        }
        *(bf16x8*)(aV1r + idx*8) = v;
    }
    // aV2r (320 chunks)
    for (int idx = t; idx < 320; idx += 256) {
        int i = idx >> 6, l2 = idx & 63, e = l2 & 15, q = l2 >> 4;
        int c0 = q*8;
        const float* dd = d2s + e*25 + i*5;
        const float* base = (c0 < 16) ? (nf + srcs[e]*240 + 160 + c0*5)
                                      : (ef + (e0 + e)*240 + 160 + (c0 - 16)*5);
        bf16x8 v;
        #pragma unroll
        for (int j = 0; j < 8; j++) {
            const float* p = base + j*5;
            float a = 0.f;
            #pragma unroll
            for (int z = 0; z < 5; z++) a += dd[z]*p[z];
            v[j] = (__bf16)a;
        }
        *(bf16x8*)(aV2r + idx*8) = v;
    }
    __syncthreads();

    // ---- T1: GEMM1  sc|w = lat@[Ws|We]  (nt 0..16),  smr = s_in@W0 (nt 17..23) ----
    {
        int col16 = lane & 15, ebase = (lane >> 4)*4;
        for (int nt = wid; nt < 24; nt += 4) {
            f32x4 acc = {0.f, 0.f, 0.f, 0.f};
            const __bf16* aB = (nt < 17) ? aLat : aSin;
            const __bf16* bB = (nt < 17) ? (wsb + OFF_WB1 + nt*2048)
                                         : (wsb + OFF_WB2 + (nt - 17)*2048);
            #pragma unroll
            for (int ks = 0; ks < 4; ks++) {
                bf16x8 a = *(const bf16x8*)(aB + (ks*64 + lane)*8);
                bf16x8 b = *(const bf16x8*)(bB + (ks*64 + lane)*8);
                acc = __builtin_amdgcn_mfma_f32_16x16x32_bf16(a, b, acc, 0, 0, 0);
            }
            int col = ((nt < 17) ? nt*16 : 272 + (nt - 17)*16) + col16;
            #pragma unroll
            for (int r = 0; r < 4; r++) Cb[(ebase + r)*388 + col] = acc[r];
        }
    }
    __syncthreads();

    // ---- T2: GEMM2  v1_m raw (3 spatial x 2 nt), v2_m raw (5 spatial) ----
    {
        int col16 = lane & 15, ebase = (lane >> 4)*4;
        for (int p = wid; p < 11; p += 4) {
            f32x4 acc = {0.f, 0.f, 0.f, 0.f};
            if (p < 6) {
                int i = p >> 1, nt = p & 1;
                #pragma unroll
                for (int ks = 0; ks < 2; ks++) {
                    bf16x8 a = *(const bf16x8*)(aV1r + ((i*2 + ks)*64 + lane)*8);
                    bf16x8 b = *(const bf16x8*)(wsb + OFF_W1 + ((nt*2 + ks)*64 + lane)*8);
                    acc = __builtin_amdgcn_mfma_f32_16x16x32_bf16(a, b, acc, 0, 0, 0);
                }
                int col = nt*16 + col16;
                #pragma unroll
                for (int r = 0; r < 4; r++) v1m[(i*16 + ebase + r)*33 + col] = acc[r];
            } else {
                int i = p - 6;
                bf16x8 a = *(const bf16x8*)(aV2r + (i*64 + lane)*8);
                bf16x8 b = *(const bf16x8*)(wsb + OFF_W2 + lane*8);
                acc = __builtin_amdgcn_mfma_f32_16x16x32_bf16(a, b, acc, 0, 0, 0);
                #pragma unroll
                for (int r = 0; r < 4; r++) v2m[(i*16 + ebase + r)*17 + col16] = acc[r];
            }
        }
    }
    __syncthreads();

    // ---- T3a: s_act (bf16 A-frag) + gates ----
    if (t < 128) {
        int ks = t >> 6, l2 = t & 63, e = l2 & 15, o0 = ks*32 + (l2 >> 4)*8;
        bf16x8 v;
        #pragma unroll
        for (int j = 0; j < 8; j++) {
            int o = o0 + j;
            float x = Cb[e*388 + 272 + o] * Cb[e*388 + o];
            v[j] = (__bf16)(x * sigf(x));
        }
        *(bf16x8*)(aSact + t*8) = v;
    }
    for (int idx = t; idx < 768; idx += 256) {
        int e = idx / 48, o = idx - e*48;
        float x = Cb[e*388 + 336 + o] * Cb[e*388 + 64 + o];
        gts[e*48 + o] = sigf(x);
    }
    __syncthreads();

    // ---- T3b/c: scale + rotate-back + gate -> bf16 A-frags ----
    for (int idx = t; idx < 512; idx += 256) {
        if (idx < 192) {
            int i = idx >> 6, l2 = idx & 63, e = l2 & 15, c0 = (l2 >> 4)*8;
            float d0 = d1s[e*9 + i*3], d1 = d1s[e*9 + i*3 + 1], d2 = d1s[e*9 + i*3 + 2];
            bf16x8 v;
            #pragma unroll
            for (int j = 0; j < 8; j++) {
                int c = c0 + j;
                float scl = Cb[e*388 + 112 + c];
                float g   = gts[e*48 + c];
                float m0 = v1m[(e)*33 + c], m1 = v1m[(16 + e)*33 + c], m2 = v1m[(32 + e)*33 + c];
                v[j] = (__bf16)(g * scl * (d0*m0 + d1*m1 + d2*m2));
            }
            *(bf16x8*)(aV1g + idx*8) = v;
        } else {
            int idx2 = idx - 192;
            int i = idx2 >> 6, l2 = idx2 & 63, e = l2 & 15, c0 = (l2 >> 4)*8;
            const float* dd = d2s + e*25 + i*5;
            bf16x8 v;
            #pragma unroll
            for (int j = 0; j < 8; j++) {
                int c = c0 + j;
                float val = 0.f;
                if (c < 16) {
                    float scl = Cb[e*388 + 144 + c];
                    float g   = gts[e*48 + 32 + c];
                    float acc = 0.f;
                    #pragma unroll
                    for (int z = 0; z < 5; z++) acc += dd[z] * v2m[(z*16 + e)*17 + c];
                    val = g * scl * acc;
                }
                v[j] = (__bf16)val;
            }
            *(bf16x8*)(aV2g + idx2*8) = v;
        }
    }
    __syncthreads();

    // ---- T4: post GEMMs, scale by env w, atomic scatter ----
    {
        int col16 = lane & 15, ebase = (lane >> 4)*4;
        for (int p = wid; p < 15; p += 4) {
            f32x4 acc = {0.f, 0.f, 0.f, 0.f};
            if (p < 4) {
                int nt = p;
                #pragma unroll
                for (int ks = 0; ks < 2; ks++) {
                    bf16x8 a = *(const bf16x8*)(aSact + (ks*64 + lane)*8);
                    bf16x8 b = *(const bf16x8*)(wsb + OFF_PW0 + ((nt*2 + ks)*64 + lane)*8);
                    acc = __builtin_amdgcn_mfma_f32_16x16x32_bf16(a, b, acc, 0, 0, 0);
                }
                int o = nt*16 + col16;
                float bias = pb0[o];
                #pragma unroll
                for (int r = 0; r < 4; r++) {
                    int e = ebase + r;
                    float val = (acc[r] + bias) * Cb[e*388 + 160 + o];
                    atomicAdd(agg + srcs[e]*240 + o, val);
                }
            } else if (p < 10) {
                int q = p - 4, i = q >> 1, nt = q & 1;
                bf16x8 a = *(const bf16x8*)(aV1g + (i*64 + lane)*8);
                bf16x8 b = *(const bf16x8*)(wsb + OFF_PW1 + (nt*64 + lane)*8);
                acc = __builtin_amdgcn_mfma_f32_16x16x32_bf16(a, b, acc, 0, 0, 0);
                int o = nt*16 + col16;
                #pragma unroll
                for (int r = 0; r < 4; r++) {
                    int e = ebase + r;
                    float val = acc[r] * Cb[e*388 + 224 + o];
                    atomicAdd(agg + srcs[e]*240 + 64 + o*3 + i, val);
                }
            } else {
                int i = p - 10;
                bf16x8 a = *(const bf16x8*)(aV2g + (i*64 + lane)*8);
                bf16x8 b = *(const bf16x8*)(wsb + OFF_PW2 + lane*8);
                acc = __builtin_amdgcn_mfma_f32_16x16x32_bf16(a, b, acc, 0, 0, 0);
                #pragma unroll
                for (int r = 0; r < 4; r++) {
                    int e = ebase + r;
                    float val = acc[r] * Cb[e*388 + 256 + col16];
                    atomicAdd(agg + srcs[e]*240 + 160 + col16*5 + i, val);
                }
            }
        }
    }
}

// ---------------------------------------------------------------------------
// Node kernel (unchanged from R2): coeffs MLP, msg MLP + LN, residual, one-hot
// ---------------------------------------------------------------------------
__global__ __launch_bounds__(256) void node_kernel(
    const float* __restrict__ nf, const float* __restrict__ mcplg,
    const float* __restrict__ ohg,
    const float* __restrict__ cW1, const float* __restrict__ cb1,
    const float* __restrict__ cW2, const float* __restrict__ cb2,
    const float* __restrict__ gsW, const float* __restrict__ gsb,
    const float* __restrict__ mW1, const float* __restrict__ mb1,
    const float* __restrict__ mW2, const float* __restrict__ mb2,
    const float* __restrict__ lng, const float* __restrict__ lnb,
    const float* __restrict__ rW0, const float* __restrict__ rb0,
    const float* __restrict__ rW1, const float* __restrict__ rW2,
    const float* __restrict__ w0g, const float* __restrict__ w1g, const float* __restrict__ w2g,
    float* out0, float* out1)
{
    __shared__ float mcp[NPB][128];
    __shared__ float ohv[NPB][96];
    __shared__ float nsr[NPB][240];
    __shared__ float anew[NPB][240];
    __shared__ float t1[NPB][128];
    __shared__ float cfs[NPB][112];
    __shared__ float scl[NPB][128];
    __shared__ float t2[NPB][128];
    __shared__ float mcn[NPB][128];
    __shared__ float gv[NPB][112];

    const int t  = threadIdx.x;
    const int n0 = blockIdx.x * NPB;

    for (int idx = t; idx < NPB * 128; idx += 256) {
        int n = idx >> 7, k = idx & 127;
        mcp[n][k] = mcplg[(n0 + n) * 128 + k];
    }
    for (int idx = t; idx < NPB * 95; idx += 256) {
        int n = idx / 95, k = idx - n * 95;
        ohv[n][k] = ohg[(n0 + n) * 95 + k];
    }
    for (int idx = t; idx < NPB * 240; idx += 256) {
        int n = idx / 240, k = idx - n * 240;
        nsr[n][k]  = nf[(n0 + n) * DIM + k];
        anew[n][k] = out0[(n0 + n) * DIM + k];
    }
    __syncthreads();

    for (int idx = t; idx < NPB * 128; idx += 256) {
        int n = idx >> 7, o = idx & 127;
        float acc = cb1[o];
        #pragma unroll 4
        for (int k = 0; k < 128; k++) acc += mcp[n][k] * cW1[k * 128 + o];
        t1[n][o] = acc * sigf(acc);
    }
    __syncthreads();

    for (int idx = t; idx < NPB * 112; idx += 256) {
        int n = idx / 112, o = idx - n * 112;
        float acc = cb2[o];
        #pragma unroll 4
        for (int k = 0; k < 128; k++) acc += t1[n][k] * cW2[k * 112 + o];
        cfs[n][o] = acc;
    }
    __syncthreads();

    for (int idx = t; idx < NPB * 240; idx += 256) {
        int n = idx / 240, d = idx - n * 240;
        int ch = (d < 64) ? d : (d < 160 ? 64 + (d - 64) / 3 : 96 + (d - 160) / 5);
        anew[n][d] = anew[n][d] * 0.25f * cfs[n][ch];
    }
    __syncthreads();

    for (int idx = t; idx < NPB * 128; idx += 256) {
        int n = idx >> 7, o = idx & 127;
        float acc = gsb[o];
        #pragma unroll 4
        for (int c = 0; c < 64; c++) acc += anew[n][c] * gsW[c * 128 + o];
        scl[n][o] = acc;
    }
    __syncthreads();

    for (int idx = t; idx < NPB * 128; idx += 256) {
        int n = idx >> 7, o = idx & 127;
        float acc = mb1[o];
        #pragma unroll 4
        for (int k = 0; k < 128; k++) acc += scl[n][k] * mW1[k * 128 + o];
        #pragma unroll 4
        for (int k = 0; k < 128; k++) acc += mcp[n][k] * mW1[(128 + k) * 128 + o];
        t2[n][o] = acc * sigf(acc);
    }
    __syncthreads();

    for (int idx = t; idx < NPB * 128; idx += 256) {
        int n = idx >> 7, o = idx & 127;
        float acc = mb2[o];
        #pragma unroll 4
        for (int k = 0; k < 128; k++) acc += t2[n][k] * mW2[k * 128 + o];
        mcn[n][o] = mcp[n][o] + acc;
    }
    __syncthreads();

    {
        int w = t >> 6, l = t & 63;
        float a = mcn[w][l], b = mcn[w][64 + l];
        float s = a + b, ss = a * a + b * b;
        #pragma unroll
        for (int off = 32; off > 0; off >>= 1) {
            s  += __shfl_down(s,  off, 64);
            ss += __shfl_down(ss, off, 64);
        }
        s  = __shfl(s, 0, 64);
        ss = __shfl(ss, 0, 64);
        float mu   = s * (1.f / 128.f);
        float var  = ss * (1.f / 128.f) - mu * mu;
        float rstd = rsqrtf(var + 1e-5f);
        out1[(n0 + w) * 128 + l]      = (a - mu) * rstd * lng[l]      + lnb[l];
        out1[(n0 + w) * 128 + 64 + l] = (b - mu) * rstd * lng[64 + l] + lnb[64 + l];
    }

    for (int idx = t; idx < NPB * 112; idx += 256) {
        int n = idx / 112, o = idx - n * 112;
        const float* wp;
        if (o < 64)      wp = w0g + o * 95;
        else if (o < 96) wp = w1g + (o - 64) * 95;
        else             wp = w2g + (o - 96) * 95;
        float acc = 0.f;
        #pragma unroll 5
        for (int k = 0; k < 95; k++) acc += ohv[n][k] * wp[k];
        gv[n][o] = acc * 0.10259783521f;
    }
    __syncthreads();

    const float c_new = 0.4472135955f;
    const float c_old = 0.8944271910f;
    for (int idx = t; idx < NPB * 240; idx += 256) {
        int n = idx / 240, d = idx - n * 240;
        float res, g;
        if (d < 64) {
            float acc = rb0[d];
            #pragma unroll 4
            for (int c = 0; c < 64; c++) acc += nsr[n][c] * rW0[c * 64 + d];
            res = acc; g = gv[n][d];
        } else if (d < 160) {
            int dd = d - 64, o = dd / 3, j = dd - o * 3;
            float acc = 0.f;
            #pragma unroll 4
            for (int c = 0; c < 32; c++) acc += nsr[n][64 + c * 3 + j] * rW1[c * 32 + o];
            res = acc; g = gv[n][64 + o];
        } else {
            int dd = d - 160, o = dd / 5, j = dd - o * 5;
            float acc = 0.f;
            #pragma unroll 4
            for (int c = 0; c < 16; c++) acc += nsr[n][160 + c * 5 + j] * rW2[c * 16 + o];
            res = acc; g = gv[n][96 + o];
        }
        float v = c_new * anew[n][d] + c_old * res;
        out0[(n0 + n) * DIM + d] = v * (1.f + g);
    }
}

extern "C" void kernel_launch(void* const* d_in, const int* in_sizes, int n_in,
                              void* d_out, int out_size, void* d_ws, size_t ws_size,
                              hipStream_t stream) {
    const float* nf      = (const float*)d_in[0];
    const float* ef      = (const float*)d_in[1];
    const float* lat     = (const float*)d_in[2];
    const float* mcpl    = (const float*)d_in[3];
    const float* ohot    = (const float*)d_in[4];
    const float* D1      = (const float*)d_in[5];
    const float* D2      = (const float*)d_in[6];
    const float* so2_W0  = (const float*)d_in[7];
    const float* so2_W1  = (const float*)d_in[8];
    const float* so2_W2  = (const float*)d_in[9];
    const float* so2_Ws  = (const float*)d_in[10];
    const float* env_W   = (const float*)d_in[11];
    const float* post_W0 = (const float*)d_in[12];
    const float* post_b0 = (const float*)d_in[13];
    const float* post_W1 = (const float*)d_in[14];
    const float* post_W2 = (const float*)d_in[15];
    const float* res_W0  = (const float*)d_in[16];
    const float* res_b0  = (const float*)d_in[17];
    const float* res_W1  = (const float*)d_in[18];
    const float* res_W2  = (const float*)d_in[19];
    const float* cpl_W1  = (const float*)d_in[20];
    const float* cpl_b1  = (const float*)d_in[21];
    const float* cpl_W2  = (const float*)d_in[22];
    const float* cpl_b2  = (const float*)d_in[23];
    const float* gs_W    = (const float*)d_in[24];
    const float* gs_b    = (const float*)d_in[25];
    const float* msg_W1  = (const float*)d_in[26];
    const float* msg_b1  = (const float*)d_in[27];
    const float* msg_W2  = (const float*)d_in[28];
    const float* msg_b2  = (const float*)d_in[29];
    const float* ln_g    = (const float*)d_in[30];
    const float* ln_b    = (const float*)d_in[31];
    const float* oh_w0   = (const float*)d_in[32];
    const float* oh_w1   = (const float*)d_in[33];
    const float* oh_w2   = (const float*)d_in[34];
    const int*   eidx    = (const int*)d_in[35];   // (2,E); row 0 = src

    float* out0 = (float*)d_out;                     // N*DIM, doubles as agg
    float* out1 = (float*)d_out + (size_t)NN * DIM;  // N*CPL
    __bf16* wsb = (__bf16*)d_ws;

    (void)hipMemsetAsync(out0, 0, (size_t)NN * DIM * sizeof(float), stream);

    prep_kernel<<<56, 256, 0, stream>>>(so2_Ws, env_W, so2_W0, so2_W1, so2_W2,
                                        post_W0, post_W1, post_W2, wsb);

    edge_mfma_kernel<<<NE / EB, 256, 0, stream>>>(
        nf, ef, lat, D1, D2, post_b0, eidx, wsb, out0);

    node_kernel<<<NN / NPB, 256, 0, stream>>>(
        nf, mcpl, ohot, cpl_W1, cpl_b1, cpl_W2, cpl_b2, gs_W, gs_b,
        msg_W1, msg_b1, msg_W2, msg_b2, ln_g, ln_b,
        res_W0, res_b0, res_W1, res_W2, oh_w0, oh_w1, oh_w2, out0, out1);
}

// Round 4
// 956.746 us; speedup vs baseline: 2.1889x; 1.0703x over previous
//
#include <hip/hip_runtime.h>

#define NN   10000
#define NE   160000
#define DIM  240
#define EB   16    // edges per block (edge kernel)
#define NPB  8     // nodes per block (node kernel)

typedef __bf16 bf16x8 __attribute__((ext_vector_type(8)));
typedef float  f32x4  __attribute__((ext_vector_type(4)));

__device__ __forceinline__ float sigf(float x) { return 1.0f / (1.0f + __expf(-x)); }

// -------- workspace layout (bf16 elements) : weight B-fragments --------
// B-fragment convention for mfma_f32_16x16x32_bf16:
//   lane l holds B[k = (l>>4)*8 + j][n = l&15], j=0..7, per (n_tile, k_step)
#define OFF_WB1 0        // [Ws|We]: N=272 (17 nt), K=128 (4 ks)
#define OFF_WB2 34816    // W0:      N=112 (7 nt),  K=128 (4 ks)
#define OFF_W1  49152    // so2_W1:  N=32 (2 nt),   K=64  (2 ks)
#define OFF_W2  51200    // so2_W2:  N=16 (1 nt),   K=32  (1 ks)
#define OFF_PW0 51712    // post_W0: N=64 (4 nt),   K=64  (2 ks)
#define OFF_PW1 55808    // post_W1: N=32 (2 nt),   K=32  (1 ks)
#define OFF_PW2 56832    // post_W2: N=16 (1 nt),   K=16 pad 32

__global__ __launch_bounds__(256) void prep_kernel(
    const float* __restrict__ Ws, const float* __restrict__ We, const float* __restrict__ W0,
    const float* __restrict__ W1, const float* __restrict__ W2,
    const float* __restrict__ pW0, const float* __restrict__ pW1, const float* __restrict__ pW2,
    __bf16* __restrict__ wsb)
{
    int tid = blockIdx.x * 256 + threadIdx.x;
    int stride = gridDim.x * 256;
    for (int idx = tid; idx < 17*4*512; idx += stride) {
        int j = idx & 7, lane = (idx >> 3) & 63, ks = (idx >> 9) & 3, nt = idx >> 11;
        int k = ks*32 + (lane >> 4)*8 + j, n = nt*16 + (lane & 15);
        float v = (n < 160) ? Ws[k*160 + n] : We[k*112 + (n - 160)];
        wsb[OFF_WB1 + idx] = (__bf16)v;
    }
    for (int idx = tid; idx < 7*4*512; idx += stride) {
        int j = idx & 7, lane = (idx >> 3) & 63, ks = (idx >> 9) & 3, nt = idx >> 11;
        int k = ks*32 + (lane >> 4)*8 + j, n = nt*16 + (lane & 15);
        wsb[OFF_WB2 + idx] = (__bf16)W0[k*112 + n];
    }
    for (int idx = tid; idx < 2*2*512; idx += stride) {
        int j = idx & 7, lane = (idx >> 3) & 63, ks = (idx >> 9) & 1, nt = idx >> 10;
        int k = ks*32 + (lane >> 4)*8 + j, n = nt*16 + (lane & 15);
        wsb[OFF_W1 + idx] = (__bf16)W1[k*32 + n];
    }
    for (int idx = tid; idx < 512; idx += stride) {
        int j = idx & 7, lane = (idx >> 3) & 63;
        int k = (lane >> 4)*8 + j, n = lane & 15;
        wsb[OFF_W2 + idx] = (__bf16)W2[k*16 + n];
    }
    for (int idx = tid; idx < 4*2*512; idx += stride) {
        int j = idx & 7, lane = (idx >> 3) & 63, ks = (idx >> 9) & 1, nt = idx >> 10;
        int k = ks*32 + (lane >> 4)*8 + j, n = nt*16 + (lane & 15);
        wsb[OFF_PW0 + idx] = (__bf16)pW0[k*64 + n];
    }
    for (int idx = tid; idx < 2*512; idx += stride) {
        int j = idx & 7, lane = (idx >> 3) & 63, nt = idx >> 9;
        int k = (lane >> 4)*8 + j, n = nt*16 + (lane & 15);
        wsb[OFF_PW1 + idx] = (__bf16)pW1[k*32 + n];
    }
    for (int idx = tid; idx < 512; idx += stride) {
        int j = idx & 7, lane = (idx >> 3) & 63;
        int k = (lane >> 4)*8 + j, n = lane & 15;
        wsb[OFF_PW2 + idx] = (k < 16) ? (__bf16)pW2[k*16 + n] : (__bf16)0.0f;
    }
}

// ---------------------------------------------------------------------------
// Edge kernel (MFMA): 16 edges/block, 256 threads (4 waves).
// Coalesced LDS staging of vector inputs; fragments built from LDS.
// ---------------------------------------------------------------------------
__global__ __launch_bounds__(256) void edge_mfma_kernel(
    const float* __restrict__ nf, const float* __restrict__ ef,
    const float* __restrict__ latg, const float* __restrict__ D1g, const float* __restrict__ D2g,
    const float* __restrict__ pb0, const int* __restrict__ srcg,
    const __bf16* __restrict__ wsb, float* agg)
{
    __shared__ __align__(16) unsigned char pool[61440];
    // P0 (aliased): vstage [16][356] f32  (0..22784)  THEN  Cb/v1m/v2m
    float*  vst  = (float*)(pool + 0);       // [16][356]: 0..176 nf[64:240], 176..352 ef[64:240]
    float*  Cb   = (float*)(pool + 0);       // [16][388]: 0..160 sc | 160..272 w | 272..384 smr
    float*  v1m  = (float*)(pool + 24832);   // [3*16][33]
    float*  v2m  = (float*)(pool + 31168);   // [5*16][17]
    // P1: A-fragments (bf16)
    __bf16* aLat = (__bf16*)(pool + 36608);  // [4 ks][64][8]   (dead after T1)
    __bf16* aSin = (__bf16*)(pool + 40704);  // [4 ks][64][8]   (dead after T1)
    __bf16* aV1r = (__bf16*)(pool + 44800);  // [3][2 ks][64][8](dead after T2)
    __bf16* aV2r = (__bf16*)(pool + 50944);  // [5][64][8]      (dead after T2)
    __bf16* aSact= (__bf16*)(pool + 36608);  // alias [2 ks][64][8]
    __bf16* aV1g = (__bf16*)(pool + 38656);  // alias [3][64][8]
    __bf16* aV2g = (__bf16*)(pool + 41728);  // alias [5][64][8]
    // P2: small persistent
    float*  d1s  = (float*)(pool + 56064);   // [16*9]
    float*  d2s  = (float*)(pool + 56640);   // [16*25]
    float*  gts  = (float*)(pool + 58240);   // [16][49]
    int*    srcs = (int*)  (pool + 61376);   // [16]

    const int t    = threadIdx.x;
    const int wid  = t >> 6, lane = t & 63;
    const int e0   = blockIdx.x * EB;

    if (t < 16) srcs[t] = srcg[e0 + t];
    __syncthreads();

    // ---- T0: coalesced staging ----
    for (int idx = t; idx < 144; idx += 256) d1s[idx] = D1g[e0*9  + idx];
    for (int idx = t; idx < 400; idx += 256) d2s[idx] = D2g[e0*25 + idx];
    // vstage: 88 float4 per edge, coalesced within rows
    for (int idx = t; idx < 16*88; idx += 256) {
        int e = idx / 88, c4 = idx - e*88;
        const float4* p = (c4 < 44) ? (const float4*)(nf + srcs[e]*240 + 64 + c4*4)
                                    : (const float4*)(ef + (e0 + e)*240 + 64 + (c4 - 44)*4);
        *(float4*)(vst + e*356 + c4*4) = *p;
    }
    // aLat / aSin: direct fragment staging (contiguous 32B per lane)
    {
        int ks = t >> 6, l2 = t & 63, e = l2 & 15, q = l2 >> 4;
        int k0 = ks*32 + q*8;
        {
            const float4* p4 = (const float4*)(latg + (e0 + e)*128 + k0);
            float4 f0 = p4[0], f1 = p4[1];
            bf16x8 v;
            v[0]=(__bf16)f0.x; v[1]=(__bf16)f0.y; v[2]=(__bf16)f0.z; v[3]=(__bf16)f0.w;
            v[4]=(__bf16)f1.x; v[5]=(__bf16)f1.y; v[6]=(__bf16)f1.z; v[7]=(__bf16)f1.w;
            *(bf16x8*)(aLat + t*8) = v;
        }
        {
            const float* s2 = (k0 < 64) ? (nf + srcs[e]*240 + k0)
                                        : (ef + (e0 + e)*240 + (k0 - 64));
            const float4* p4 = (const float4*)s2;
            float4 f0 = p4[0], f1 = p4[1];
            bf16x8 v;
            v[0]=(__bf16)f0.x; v[1]=(__bf16)f0.y; v[2]=(__bf16)f0.z; v[3]=(__bf16)f0.w;
            v[4]=(__bf16)f1.x; v[5]=(__bf16)f1.y; v[6]=(__bf16)f1.z; v[7]=(__bf16)f1.w;
            *(bf16x8*)(aSin + t*8) = v;
        }
    }
    __syncthreads();

    // ---- T0b: build rotated A-fragments from LDS ----
    for (int idx = t; idx < 384; idx += 256) {
        int i = idx >> 7, rem = idx & 127, ks = rem >> 6, l2 = rem & 63;
        int e = l2 & 15, q = l2 >> 4;
        int c0 = ks*32 + q*8;
        float da = d1s[e*9 + i*3 + 0], db = d1s[e*9 + i*3 + 1], dc = d1s[e*9 + i*3 + 2];
        const float* ve = vst + e*356;
        bf16x8 v;
        #pragma unroll
        for (int j = 0; j < 8; j++) {
            int c = c0 + j;
            const float* p = (c < 32) ? (ve + c*3) : (ve + 176 + (c - 32)*3);
            v[j] = (__bf16)(da*p[0] + db*p[1] + dc*p[2]);
        }
        *(bf16x8*)(aV1r + idx*8) = v;
    }
    for (int idx = t; idx < 320; idx += 256) {
        int i = idx >> 6, l2 = idx & 63, e = l2 & 15, q = l2 >> 4;
        int c0 = q*8;
        const float* dd = d2s + e*25 + i*5;
        const float* ve = vst + e*356;
        bf16x8 v;
        #pragma unroll
        for (int j = 0; j < 8; j++) {
            int c = c0 + j;
            const float* p = (c < 16) ? (ve + 96 + c*5) : (ve + 272 + (c - 16)*5);
            float a = 0.f;
            #pragma unroll
            for (int z = 0; z < 5; z++) a += dd[z]*p[z];
            v[j] = (__bf16)a;
        }
        *(bf16x8*)(aV2r + idx*8) = v;
    }
    __syncthreads();   // vstage dead; Cb region live from here

    // ---- T1: GEMM1  sc|w = lat@[Ws|We] (nt 0..16), smr = s_in@W0 (nt 17..23) ----
    {
        int col16 = lane & 15, ebase = (lane >> 4)*4;
        for (int nt = wid; nt < 24; nt += 4) {
            f32x4 acc = {0.f, 0.f, 0.f, 0.f};
            const __bf16* aB = (nt < 17) ? aLat : aSin;
            const __bf16* bB = (nt < 17) ? (wsb + OFF_WB1 + nt*2048)
                                         : (wsb + OFF_WB2 + (nt - 17)*2048);
            #pragma unroll
            for (int ks = 0; ks < 4; ks++) {
                bf16x8 a = *(const bf16x8*)(aB + (ks*64 + lane)*8);
                bf16x8 b = *(const bf16x8*)(bB + (ks*64 + lane)*8);
                acc = __builtin_amdgcn_mfma_f32_16x16x32_bf16(a, b, acc, 0, 0, 0);
            }
            int col = ((nt < 17) ? nt*16 : 272 + (nt - 17)*16) + col16;
            #pragma unroll
            for (int r = 0; r < 4; r++) Cb[(ebase + r)*388 + col] = acc[r];
        }
    }
    __syncthreads();

    // ---- T2: GEMM2  v1_m raw (3 x 2 nt), v2_m raw (5) ----
    {
        int col16 = lane & 15, ebase = (lane >> 4)*4;
        for (int p = wid; p < 11; p += 4) {
            f32x4 acc = {0.f, 0.f, 0.f, 0.f};
            if (p < 6) {
                int i = p >> 1, nt = p & 1;
                #pragma unroll
                for (int ks = 0; ks < 2; ks++) {
                    bf16x8 a = *(const bf16x8*)(aV1r + ((i*2 + ks)*64 + lane)*8);
                    bf16x8 b = *(const bf16x8*)(wsb + OFF_W1 + ((nt*2 + ks)*64 + lane)*8);
                    acc = __builtin_amdgcn_mfma_f32_16x16x32_bf16(a, b, acc, 0, 0, 0);
                }
                int col = nt*16 + col16;
                #pragma unroll
                for (int r = 0; r < 4; r++) v1m[(i*16 + ebase + r)*33 + col] = acc[r];
            } else {
                int i = p - 6;
                bf16x8 a = *(const bf16x8*)(aV2r + (i*64 + lane)*8);
                bf16x8 b = *(const bf16x8*)(wsb + OFF_W2 + lane*8);
                acc = __builtin_amdgcn_mfma_f32_16x16x32_bf16(a, b, acc, 0, 0, 0);
                #pragma unroll
                for (int r = 0; r < 4; r++) v2m[(i*16 + ebase + r)*17 + col16] = acc[r];
            }
        }
    }
    __syncthreads();

    // ---- T3a: s_act (bf16 A-frag) + gates ----
    if (t < 128) {
        int ks = t >> 6, l2 = t & 63, e = l2 & 15, o0 = ks*32 + (l2 >> 4)*8;
        bf16x8 v;
        #pragma unroll
        for (int j = 0; j < 8; j++) {
            int o = o0 + j;
            float x = Cb[e*388 + 272 + o] * Cb[e*388 + o];
            v[j] = (__bf16)(x * sigf(x));
        }
        *(bf16x8*)(aSact + t*8) = v;
    }
    for (int idx = t; idx < 768; idx += 256) {
        int e = idx / 48, o = idx - e*48;
        float x = Cb[e*388 + 336 + o] * Cb[e*388 + 64 + o];
        gts[e*49 + o] = sigf(x);
    }
    __syncthreads();

    // ---- T3b: scale + rotate-back + gate -> bf16 A-frags ----
    for (int idx = t; idx < 512; idx += 256) {
        if (idx < 192) {
            int i = idx >> 6, l2 = idx & 63, e = l2 & 15, c0 = (l2 >> 4)*8;
            float d0 = d1s[e*9 + i*3], d1 = d1s[e*9 + i*3 + 1], d2 = d1s[e*9 + i*3 + 2];
            bf16x8 v;
            #pragma unroll
            for (int j = 0; j < 8; j++) {
                int c = c0 + j;
                float scl = Cb[e*388 + 112 + c];
                float g   = gts[e*49 + c];
                float m0 = v1m[e*33 + c], m1 = v1m[(16 + e)*33 + c], m2 = v1m[(32 + e)*33 + c];
                v[j] = (__bf16)(g * scl * (d0*m0 + d1*m1 + d2*m2));
            }
            *(bf16x8*)(aV1g + idx*8) = v;
        } else {
            int idx2 = idx - 192;
            int i = idx2 >> 6, l2 = idx2 & 63, e = l2 & 15, c0 = (l2 >> 4)*8;
            const float* dd = d2s + e*25 + i*5;
            bf16x8 v;
            #pragma unroll
            for (int j = 0; j < 8; j++) {
                int c = c0 + j;
                float val = 0.f;
                if (c < 16) {
                    float scl = Cb[e*388 + 144 + c];
                    float g   = gts[e*49 + 32 + c];
                    float acc = 0.f;
                    #pragma unroll
                    for (int z = 0; z < 5; z++) acc += dd[z] * v2m[(z*16 + e)*17 + c];
                    val = g * scl * acc;
                }
                v[j] = (__bf16)val;
            }
            *(bf16x8*)(aV2g + idx2*8) = v;
        }
    }
    __syncthreads();

    // ---- T4: post GEMMs, scale by env w, atomic scatter ----
    {
        int col16 = lane & 15, ebase = (lane >> 4)*4;
        for (int p = wid; p < 15; p += 4) {
            f32x4 acc = {0.f, 0.f, 0.f, 0.f};
            if (p < 4) {
                int nt = p;
                #pragma unroll
                for (int ks = 0; ks < 2; ks++) {
                    bf16x8 a = *(const bf16x8*)(aSact + (ks*64 + lane)*8);
                    bf16x8 b = *(const bf16x8*)(wsb + OFF_PW0 + ((nt*2 + ks)*64 + lane)*8);
                    acc = __builtin_amdgcn_mfma_f32_16x16x32_bf16(a, b, acc, 0, 0, 0);
                }
                int o = nt*16 + col16;
                float bias = pb0[o];
                #pragma unroll
                for (int r = 0; r < 4; r++) {
                    int e = ebase + r;
                    float val = (acc[r] + bias) * Cb[e*388 + 160 + o];
                    atomicAdd(agg + srcs[e]*240 + o, val);
                }
            } else if (p < 10) {
                int q = p - 4, i = q >> 1, nt = q & 1;
                bf16x8 a = *(const bf16x8*)(aV1g + (i*64 + lane)*8);
                bf16x8 b = *(const bf16x8*)(wsb + OFF_PW1 + (nt*64 + lane)*8);
                acc = __builtin_amdgcn_mfma_f32_16x16x32_bf16(a, b, acc, 0, 0, 0);
                int o = nt*16 + col16;
                #pragma unroll
                for (int r = 0; r < 4; r++) {
                    int e = ebase + r;
                    float val = acc[r] * Cb[e*388 + 224 + o];
                    atomicAdd(agg + srcs[e]*240 + 64 + o*3 + i, val);
                }
            } else {
                int i = p - 10;
                bf16x8 a = *(const bf16x8*)(aV2g + (i*64 + lane)*8);
                bf16x8 b = *(const bf16x8*)(wsb + OFF_PW2 + lane*8);
                acc = __builtin_amdgcn_mfma_f32_16x16x32_bf16(a, b, acc, 0, 0, 0);
                #pragma unroll
                for (int r = 0; r < 4; r++) {
                    int e = ebase + r;
                    float val = acc[r] * Cb[e*388 + 256 + col16];
                    atomicAdd(agg + srcs[e]*240 + 160 + col16*5 + i, val);
                }
            }
        }
    }
}

// ---------------------------------------------------------------------------
// Node kernel: 8 nodes/block; each thread computes 1 column x 4 nodes
// (one weight load feeds 4 FMAs). Group g = t>>7 handles nodes 4g..4g+3.
// ---------------------------------------------------------------------------
__global__ __launch_bounds__(256) void node_kernel(
    const float* __restrict__ nf, const float* __restrict__ mcplg,
    const float* __restrict__ ohg,
    const float* __restrict__ cW1, const float* __restrict__ cb1,
    const float* __restrict__ cW2, const float* __restrict__ cb2,
    const float* __restrict__ gsW, const float* __restrict__ gsb,
    const float* __restrict__ mW1, const float* __restrict__ mb1,
    const float* __restrict__ mW2, const float* __restrict__ mb2,
    const float* __restrict__ lng, const float* __restrict__ lnb,
    const float* __restrict__ rW0, const float* __restrict__ rb0,
    const float* __restrict__ rW1, const float* __restrict__ rW2,
    const float* __restrict__ w0g, const float* __restrict__ w1g, const float* __restrict__ w2g,
    float* out0, float* out1)
{
    __shared__ float mcp[NPB][128];
    __shared__ float ohv[NPB][96];
    __shared__ float nsr[NPB][240];
    __shared__ float anew[NPB][240];
    __shared__ float t1s[NPB][128];
    __shared__ float cfs[NPB][112];
    __shared__ float scl[NPB][128];
    __shared__ float t2s[NPB][128];
    __shared__ float mcn[NPB][128];
    __shared__ float gv[NPB][112];

    const int t  = threadIdx.x;
    const int g  = t >> 7;        // wave-uniform
    const int o  = t & 127;
    const int nb = g * 4;
    const int n0 = blockIdx.x * NPB;

    for (int idx = t; idx < NPB * 128; idx += 256) {
        int n = idx >> 7, k = idx & 127;
        mcp[n][k] = mcplg[(n0 + n) * 128 + k];
    }
    for (int idx = t; idx < NPB * 95; idx += 256) {
        int n = idx / 95, k = idx - n * 95;
        ohv[n][k] = ohg[(n0 + n) * 95 + k];
    }
    for (int idx = t; idx < NPB * 240; idx += 256) {
        int n = idx / 240, k = idx - n * 240;
        nsr[n][k]  = nf[(n0 + n) * DIM + k];
        anew[n][k] = out0[(n0 + n) * DIM + k];   // agg (atomic sums)
    }
    __syncthreads();

    // t1 = silu(mcp @ cW1 + cb1)
    {
        float a0 = cb1[o], a1 = a0, a2 = a0, a3 = a0;
        #pragma unroll 4
        for (int k = 0; k < 128; k++) {
            float w = cW1[k * 128 + o];
            a0 += mcp[nb+0][k] * w; a1 += mcp[nb+1][k] * w;
            a2 += mcp[nb+2][k] * w; a3 += mcp[nb+3][k] * w;
        }
        t1s[nb+0][o] = a0 * sigf(a0); t1s[nb+1][o] = a1 * sigf(a1);
        t1s[nb+2][o] = a2 * sigf(a2); t1s[nb+3][o] = a3 * sigf(a3);
    }
    __syncthreads();

    // coeffs = t1 @ cW2 + cb2
    if (o < 112) {
        float a0 = cb2[o], a1 = a0, a2 = a0, a3 = a0;
        #pragma unroll 4
        for (int k = 0; k < 128; k++) {
            float w = cW2[k * 112 + o];
            a0 += t1s[nb+0][k] * w; a1 += t1s[nb+1][k] * w;
            a2 += t1s[nb+2][k] * w; a3 += t1s[nb+3][k] * w;
        }
        cfs[nb+0][o] = a0; cfs[nb+1][o] = a1; cfs[nb+2][o] = a2; cfs[nb+3][o] = a3;
    }
    __syncthreads();

    // new_nf = agg * AVG_NEI^-0.5 * coeffs[SCALE_IDX]
    for (int idx = t; idx < NPB * 240; idx += 256) {
        int n = idx / 240, d = idx - n * 240;
        int ch = (d < 64) ? d : (d < 160 ? 64 + (d - 64) / 3 : 96 + (d - 160) / 5);
        anew[n][d] = anew[n][d] * 0.25f * cfs[n][ch];
    }
    __syncthreads();

    // scal = new_nf[:,:64] @ gsW + gsb
    {
        float a0 = gsb[o], a1 = a0, a2 = a0, a3 = a0;
        #pragma unroll 4
        for (int c = 0; c < 64; c++) {
            float w = gsW[c * 128 + o];
            a0 += anew[nb+0][c] * w; a1 += anew[nb+1][c] * w;
            a2 += anew[nb+2][c] * w; a3 += anew[nb+3][c] * w;
        }
        scl[nb+0][o] = a0; scl[nb+1][o] = a1; scl[nb+2][o] = a2; scl[nb+3][o] = a3;
    }
    __syncthreads();

    // t2 = silu([scal, mcp] @ mW1 + mb1)
    {
        float a0 = mb1[o], a1 = a0, a2 = a0, a3 = a0;
        #pragma unroll 4
        for (int k = 0; k < 128; k++) {
            float w = mW1[k * 128 + o];
            a0 += scl[nb+0][k] * w; a1 += scl[nb+1][k] * w;
            a2 += scl[nb+2][k] * w; a3 += scl[nb+3][k] * w;
        }
        #pragma unroll 4
        for (int k = 0; k < 128; k++) {
            float w = mW1[(128 + k) * 128 + o];
            a0 += mcp[nb+0][k] * w; a1 += mcp[nb+1][k] * w;
            a2 += mcp[nb+2][k] * w; a3 += mcp[nb+3][k] * w;
        }
        t2s[nb+0][o] = a0 * sigf(a0); t2s[nb+1][o] = a1 * sigf(a1);
        t2s[nb+2][o] = a2 * sigf(a2); t2s[nb+3][o] = a3 * sigf(a3);
    }
    __syncthreads();

    // mcn = mcp + t2 @ mW2 + mb2
    {
        float a0 = mb2[o], a1 = a0, a2 = a0, a3 = a0;
        #pragma unroll 4
        for (int k = 0; k < 128; k++) {
            float w = mW2[k * 128 + o];
            a0 += t2s[nb+0][k] * w; a1 += t2s[nb+1][k] * w;
            a2 += t2s[nb+2][k] * w; a3 += t2s[nb+3][k] * w;
        }
        mcn[nb+0][o] = mcp[nb+0][o] + a0; mcn[nb+1][o] = mcp[nb+1][o] + a1;
        mcn[nb+2][o] = mcp[nb+2][o] + a2; mcn[nb+3][o] = mcp[nb+3][o] + a3;
    }
    __syncthreads();

    // LayerNorm: 32-lane group per node (8 nodes, 256 threads)
    {
        int n = t >> 5, l = t & 31;
        float x0 = mcn[n][l], x1 = mcn[n][32 + l], x2 = mcn[n][64 + l], x3 = mcn[n][96 + l];
        float s = x0 + x1 + x2 + x3;
        float ss = x0*x0 + x1*x1 + x2*x2 + x3*x3;
        #pragma unroll
        for (int off = 16; off > 0; off >>= 1) {
            s  += __shfl_down(s,  off, 32);
            ss += __shfl_down(ss, off, 32);
        }
        s  = __shfl(s, 0, 32);
        ss = __shfl(ss, 0, 32);
        float mu   = s * (1.f / 128.f);
        float var  = ss * (1.f / 128.f) - mu * mu;
        float rstd = rsqrtf(var + 1e-5f);
        float* op = out1 + (n0 + n) * 128;
        op[l]      = (x0 - mu) * rstd * lng[l]      + lnb[l];
        op[32 + l] = (x1 - mu) * rstd * lng[32 + l] + lnb[32 + l];
        op[64 + l] = (x2 - mu) * rstd * lng[64 + l] + lnb[64 + l];
        op[96 + l] = (x3 - mu) * rstd * lng[96 + l] + lnb[96 + l];
    }

    // one-hot gains (per-thread contiguous weight rows)
    if (o < 112) {
        const float* wp;
        if (o < 64)      wp = w0g + o * 95;
        else if (o < 96) wp = w1g + (o - 64) * 95;
        else             wp = w2g + (o - 96) * 95;
        float a0 = 0.f, a1 = 0.f, a2 = 0.f, a3 = 0.f;
        #pragma unroll 5
        for (int k = 0; k < 95; k++) {
            float w = wp[k];
            a0 += ohv[nb+0][k] * w; a1 += ohv[nb+1][k] * w;
            a2 += ohv[nb+2][k] * w; a3 += ohv[nb+3][k] * w;
        }
        const float inv = 0.10259783521f;   // 1/sqrt(95)
        gv[nb+0][o] = a0 * inv; gv[nb+1][o] = a1 * inv;
        gv[nb+2][o] = a2 * inv; gv[nb+3][o] = a3 * inv;
    }
    __syncthreads();

    // residual + combine + one-hot gain, write out0
    const float c_new = 0.4472135955f;   // sigmoid(0)*rsqrt(1.25)
    const float c_old = 0.8944271910f;   // rsqrt(1.25)
    for (int idx = t; idx < NPB * 240; idx += 256) {
        int n = idx / 240, d = idx - n * 240;
        float res, gg;
        if (d < 64) {
            float acc = rb0[d];
            #pragma unroll 4
            for (int c = 0; c < 64; c++) acc += nsr[n][c] * rW0[c * 64 + d];
            res = acc; gg = gv[n][d];
        } else if (d < 160) {
            int dd = d - 64, oo = dd / 3, j = dd - oo * 3;
            float acc = 0.f;
            #pragma unroll 4
            for (int c = 0; c < 32; c++) acc += nsr[n][64 + c * 3 + j] * rW1[c * 32 + oo];
            res = acc; gg = gv[n][64 + oo];
        } else {
            int dd = d - 160, oo = dd / 5, j = dd - oo * 5;
            float acc = 0.f;
            #pragma unroll 4
            for (int c = 0; c < 16; c++) acc += nsr[n][160 + c * 5 + j] * rW2[c * 16 + oo];
            res = acc; gg = gv[n][96 + oo];
        }
        float v = c_new * anew[n][d] + c_old * res;
        out0[(n0 + n) * DIM + d] = v * (1.f + gg);
    }
}

extern "C" void kernel_launch(void* const* d_in, const int* in_sizes, int n_in,
                              void* d_out, int out_size, void* d_ws, size_t ws_size,
                              hipStream_t stream) {
    const float* nf      = (const float*)d_in[0];
    const float* ef      = (const float*)d_in[1];
    const float* lat     = (const float*)d_in[2];
    const float* mcpl    = (const float*)d_in[3];
    const float* ohot    = (const float*)d_in[4];
    const float* D1      = (const float*)d_in[5];
    const float* D2      = (const float*)d_in[6];
    const float* so2_W0  = (const float*)d_in[7];
    const float* so2_W1  = (const float*)d_in[8];
    const float* so2_W2  = (const float*)d_in[9];
    const float* so2_Ws  = (const float*)d_in[10];
    const float* env_W   = (const float*)d_in[11];
    const float* post_W0 = (const float*)d_in[12];
    const float* post_b0 = (const float*)d_in[13];
    const float* post_W1 = (const float*)d_in[14];
    const float* post_W2 = (const float*)d_in[15];
    const float* res_W0  = (const float*)d_in[16];
    const float* res_b0  = (const float*)d_in[17];
    const float* res_W1  = (const float*)d_in[18];
    const float* res_W2  = (const float*)d_in[19];
    const float* cpl_W1  = (const float*)d_in[20];
    const float* cpl_b1  = (const float*)d_in[21];
    const float* cpl_W2  = (const float*)d_in[22];
    const float* cpl_b2  = (const float*)d_in[23];
    const float* gs_W    = (const float*)d_in[24];
    const float* gs_b    = (const float*)d_in[25];
    const float* msg_W1  = (const float*)d_in[26];
    const float* msg_b1  = (const float*)d_in[27];
    const float* msg_W2  = (const float*)d_in[28];
    const float* msg_b2  = (const float*)d_in[29];
    const float* ln_g    = (const float*)d_in[30];
    const float* ln_b    = (const float*)d_in[31];
    const float* oh_w0   = (const float*)d_in[32];
    const float* oh_w1   = (const float*)d_in[33];
    const float* oh_w2   = (const float*)d_in[34];
    const int*   eidx    = (const int*)d_in[35];   // (2,E); row 0 = src

    float* out0 = (float*)d_out;                     // N*DIM, doubles as agg
    float* out1 = (float*)d_out + (size_t)NN * DIM;  // N*CPL
    __bf16* wsb = (__bf16*)d_ws;

    (void)hipMemsetAsync(out0, 0, (size_t)NN * DIM * sizeof(float), stream);

    prep_kernel<<<56, 256, 0, stream>>>(so2_Ws, env_W, so2_W0, so2_W1, so2_W2,
                                        post_W0, post_W1, post_W2, wsb);

    edge_mfma_kernel<<<NE / EB, 256, 0, stream>>>(
        nf, ef, lat, D1, D2, post_b0, eidx, wsb, out0);

    node_kernel<<<NN / NPB, 256, 0, stream>>>(
        nf, mcpl, ohot, cpl_W1, cpl_b1, cpl_W2, cpl_b2, gs_W, gs_b,
        msg_W1, msg_b1, msg_W2, msg_b2, ln_g, ln_b,
        res_W0, res_b0, res_W1, res_W2, oh_w0, oh_w1, oh_w2, out0, out1);
}

// Round 5
// 886.308 us; speedup vs baseline: 2.3629x; 1.0795x over previous
//
#include <hip/hip_runtime.h>

#define NN   10000
#define NE   160000
#define DIM  240
#define EB   16    // edges per block (edge kernel)
#define NPB  16    // nodes per block (node kernel)

typedef __bf16 bf16x8 __attribute__((ext_vector_type(8)));
typedef __bf16 bf16x4 __attribute__((ext_vector_type(4)));
typedef float  f32x4  __attribute__((ext_vector_type(4)));

__device__ __forceinline__ float sigf(float x) { return 1.0f / (1.0f + __expf(-x)); }

// -------- workspace layout --------
// bf16 B-fragments for mfma_f32_16x16x32_bf16:
//   lane l holds B[k=(l>>4)*8+j][n=l&15], j=0..7, per (nt, ks)
#define OFF_WB1 0        // [Ws|We]: N=272 (17 nt), K=128 (4 ks)
#define OFF_WB2 34816    // W0:      N=112 (7 nt),  K=128 (4 ks)
#define OFF_W1  49152    // so2_W1:  N=32 (2 nt),   K=64  (2 ks)
#define OFF_W2  51200    // so2_W2:  N=16 (1 nt),   K=32  (1 ks)
#define OFF_PW0 51712    // post_W0: N=64 (4 nt),   K=64  (2 ks)
#define OFF_PW1 55808    // post_W1: N=32 (2 nt),   K=32  (1 ks)
#define OFF_PW2 56832    // post_W2: N=16 (1 nt),   K=16 pad 32
#define OHT_BYTE_OFF 131072   // float [96][112]: transposed oh weights * 1/sqrt(95)

__global__ __launch_bounds__(256) void prep_kernel(
    const float* __restrict__ Ws, const float* __restrict__ We, const float* __restrict__ W0,
    const float* __restrict__ W1, const float* __restrict__ W2,
    const float* __restrict__ pW0, const float* __restrict__ pW1, const float* __restrict__ pW2,
    const float* __restrict__ w0g, const float* __restrict__ w1g, const float* __restrict__ w2g,
    __bf16* __restrict__ wsb, float* __restrict__ ohT)
{
    int tid = blockIdx.x * 256 + threadIdx.x;
    int stride = gridDim.x * 256;
    for (int idx = tid; idx < 17*4*512; idx += stride) {
        int j = idx & 7, lane = (idx >> 3) & 63, ks = (idx >> 9) & 3, nt = idx >> 11;
        int k = ks*32 + (lane >> 4)*8 + j, n = nt*16 + (lane & 15);
        float v = (n < 160) ? Ws[k*160 + n] : We[k*112 + (n - 160)];
        wsb[OFF_WB1 + idx] = (__bf16)v;
    }
    for (int idx = tid; idx < 7*4*512; idx += stride) {
        int j = idx & 7, lane = (idx >> 3) & 63, ks = (idx >> 9) & 3, nt = idx >> 11;
        int k = ks*32 + (lane >> 4)*8 + j, n = nt*16 + (lane & 15);
        wsb[OFF_WB2 + idx] = (__bf16)W0[k*112 + n];
    }
    for (int idx = tid; idx < 2*2*512; idx += stride) {
        int j = idx & 7, lane = (idx >> 3) & 63, ks = (idx >> 9) & 1, nt = idx >> 10;
        int k = ks*32 + (lane >> 4)*8 + j, n = nt*16 + (lane & 15);
        wsb[OFF_W1 + idx] = (__bf16)W1[k*32 + n];
    }
    for (int idx = tid; idx < 512; idx += stride) {
        int j = idx & 7, lane = (idx >> 3) & 63;
        int k = (lane >> 4)*8 + j, n = lane & 15;
        wsb[OFF_W2 + idx] = (__bf16)W2[k*16 + n];
    }
    for (int idx = tid; idx < 4*2*512; idx += stride) {
        int j = idx & 7, lane = (idx >> 3) & 63, ks = (idx >> 9) & 1, nt = idx >> 10;
        int k = ks*32 + (lane >> 4)*8 + j, n = nt*16 + (lane & 15);
        wsb[OFF_PW0 + idx] = (__bf16)pW0[k*64 + n];
    }
    for (int idx = tid; idx < 2*512; idx += stride) {
        int j = idx & 7, lane = (idx >> 3) & 63, nt = idx >> 9;
        int k = (lane >> 4)*8 + j, n = nt*16 + (lane & 15);
        wsb[OFF_PW1 + idx] = (__bf16)pW1[k*32 + n];
    }
    for (int idx = tid; idx < 512; idx += stride) {
        int j = idx & 7, lane = (idx >> 3) & 63;
        int k = (lane >> 4)*8 + j, n = lane & 15;
        wsb[OFF_PW2 + idx] = (k < 16) ? (__bf16)pW2[k*16 + n] : (__bf16)0.0f;
    }
    // transposed one-hot weights (padded K 95->96), scale folded in
    for (int idx = tid; idx < 96*112; idx += stride) {
        int k = idx / 112, n2 = idx - k*112;
        float v = 0.f;
        if (k < 95) {
            if (n2 < 64)      v = w0g[n2*95 + k];
            else if (n2 < 96) v = w1g[(n2-64)*95 + k];
            else              v = w2g[(n2-96)*95 + k];
        }
        ohT[idx] = v * 0.10259783521f;
    }
}

// ---------------------------------------------------------------------------
// Edge kernel (MFMA): 16 edges/block, 256 threads, 36.5 KB LDS -> 4 blocks/CU
// ---------------------------------------------------------------------------
__global__ __launch_bounds__(256, 4) void edge_mfma_kernel(
    const float* __restrict__ nf, const float* __restrict__ ef,
    const float* __restrict__ latg, const float* __restrict__ D1g, const float* __restrict__ D2g,
    const float* __restrict__ pb0, const int* __restrict__ srcg,
    const __bf16* __restrict__ wsb, float* agg)
{
    __shared__ __align__(16) unsigned char pool[37376];
    __bf16* Cb   = (__bf16*)(pool + 0);       // [16][392] (after T1)
    __bf16* vst  = (__bf16*)(pool + 0);       // [16][360] (T0 only, alias)
    __bf16* aLat = (__bf16*)(pool + 12544);   // [4][64][8]   dead after T1
    __bf16* aSin = (__bf16*)(pool + 16640);   // [4][64][8]   dead after T1
    __bf16* v1m  = (__bf16*)(pool + 12544);   // [48][33]     alias, from T2
    __bf16* v2m  = (__bf16*)(pool + 15712);   // [80][17]     alias, from T2
    __bf16* aV1r = (__bf16*)(pool + 20736);   // [6][64][8]   dead after T2
    __bf16* aV2r = (__bf16*)(pool + 26880);   // [5][64][8]   dead after T2
    __bf16* aSact= (__bf16*)(pool + 20736);   // [2][64][8]   alias, from T3
    __bf16* aV1g = (__bf16*)(pool + 22784);   // [3][64][8]
    __bf16* aV2g = (__bf16*)(pool + 25856);   // [5][64][8]
    float*  d1s  = (float*)(pool + 32000);    // [16*9]
    float*  d2s  = (float*)(pool + 32576);    // [16*25]
    float*  gts  = (float*)(pool + 34176);    // [16][49]
    int*    srcs = (int*)  (pool + 37312);    // [16]

    const int t    = threadIdx.x;
    const int wid  = t >> 6, lane = t & 63;
    const int e0   = blockIdx.x * EB;

    if (t < 16) srcs[t] = srcg[e0 + t];
    __syncthreads();

    // ---- T0: staging ----
    for (int idx = t; idx < 144; idx += 256) d1s[idx] = D1g[e0*9  + idx];
    for (int idx = t; idx < 400; idx += 256) d2s[idx] = D2g[e0*25 + idx];
    for (int idx = t; idx < 16*88; idx += 256) {
        int e = idx / 88, c4 = idx - e*88;
        const float4* p = (c4 < 44) ? (const float4*)(nf + srcs[e]*240 + 64 + c4*4)
                                    : (const float4*)(ef + (e0 + e)*240 + 64 + (c4 - 44)*4);
        float4 f = *p;
        bf16x4 v = { (__bf16)f.x, (__bf16)f.y, (__bf16)f.z, (__bf16)f.w };
        *(bf16x4*)(vst + e*360 + c4*4) = v;
    }
    {
        int ks = t >> 6, l2 = t & 63, e = l2 & 15, q = l2 >> 4;
        int k0 = ks*32 + q*8;
        {
            const float4* p4 = (const float4*)(latg + (e0 + e)*128 + k0);
            float4 f0 = p4[0], f1 = p4[1];
            bf16x8 v;
            v[0]=(__bf16)f0.x; v[1]=(__bf16)f0.y; v[2]=(__bf16)f0.z; v[3]=(__bf16)f0.w;
            v[4]=(__bf16)f1.x; v[5]=(__bf16)f1.y; v[6]=(__bf16)f1.z; v[7]=(__bf16)f1.w;
            *(bf16x8*)(aLat + t*8) = v;
        }
        {
            const float* s2 = (k0 < 64) ? (nf + srcs[e]*240 + k0)
                                        : (ef + (e0 + e)*240 + (k0 - 64));
            const float4* p4 = (const float4*)s2;
            float4 f0 = p4[0], f1 = p4[1];
            bf16x8 v;
            v[0]=(__bf16)f0.x; v[1]=(__bf16)f0.y; v[2]=(__bf16)f0.z; v[3]=(__bf16)f0.w;
            v[4]=(__bf16)f1.x; v[5]=(__bf16)f1.y; v[6]=(__bf16)f1.z; v[7]=(__bf16)f1.w;
            *(bf16x8*)(aSin + t*8) = v;
        }
    }
    __syncthreads();

    // ---- T0b: rotated A-fragments from LDS ----
    for (int idx = t; idx < 384; idx += 256) {
        int i = idx >> 7, rem = idx & 127, ks = rem >> 6, l2 = rem & 63;
        int e = l2 & 15, q = l2 >> 4;
        int c0 = ks*32 + q*8;
        float da = d1s[e*9 + i*3 + 0], db = d1s[e*9 + i*3 + 1], dc = d1s[e*9 + i*3 + 2];
        const __bf16* ve = vst + e*360;
        bf16x8 v;
        #pragma unroll
        for (int j = 0; j < 8; j++) {
            int c = c0 + j;
            const __bf16* p = (c < 32) ? (ve + c*3) : (ve + 176 + (c - 32)*3);
            v[j] = (__bf16)(da*(float)p[0] + db*(float)p[1] + dc*(float)p[2]);
        }
        *(bf16x8*)(aV1r + idx*8) = v;
    }
    for (int idx = t; idx < 320; idx += 256) {
        int i = idx >> 6, l2 = idx & 63, e = l2 & 15, q = l2 >> 4;
        int c0 = q*8;
        const float* dd = d2s + e*25 + i*5;
        const __bf16* ve = vst + e*360;
        bf16x8 v;
        #pragma unroll
        for (int j = 0; j < 8; j++) {
            int c = c0 + j;
            const __bf16* p = (c < 16) ? (ve + 96 + c*5) : (ve + 272 + (c - 16)*5);
            float a = 0.f;
            #pragma unroll
            for (int z = 0; z < 5; z++) a += dd[z]*(float)p[z];
            v[j] = (__bf16)a;
        }
        *(bf16x8*)(aV2r + idx*8) = v;
    }
    __syncthreads();   // vst dead; Cb region live from here

    // ---- T1: GEMM1  sc|w = lat@[Ws|We] (nt 0..16), smr = s_in@W0 (nt 17..23)
    //      A-frags in registers; 6 unrolled tiles -> up to 24 B-loads in flight
    {
        int col16 = lane & 15, ebase = (lane >> 4)*4;
        bf16x8 aL[4], aS[4];
        #pragma unroll
        for (int ks = 0; ks < 4; ks++) {
            aL[ks] = *(const bf16x8*)(aLat + (ks*64 + lane)*8);
            aS[ks] = *(const bf16x8*)(aSin + (ks*64 + lane)*8);
        }
        #pragma unroll
        for (int it = 0; it < 6; it++) {
            int nt = wid + it*4;
            bool isLat = nt < 17;
            const __bf16* bB = isLat ? (wsb + OFF_WB1 + nt*2048)
                                     : (wsb + OFF_WB2 + (nt - 17)*2048);
            f32x4 acc = {0.f, 0.f, 0.f, 0.f};
            #pragma unroll
            for (int ks = 0; ks < 4; ks++) {
                bf16x8 b = *(const bf16x8*)(bB + (ks*64 + lane)*8);
                acc = __builtin_amdgcn_mfma_f32_16x16x32_bf16(isLat ? aL[ks] : aS[ks], b, acc, 0, 0, 0);
            }
            int col = (isLat ? nt*16 : 272 + (nt - 17)*16) + col16;
            #pragma unroll
            for (int r = 0; r < 4; r++) Cb[(ebase + r)*392 + col] = (__bf16)acc[r];
        }
    }
    __syncthreads();

    // ---- T2: v1_m raw (3 x 2 nt), v2_m raw (5) ----
    {
        int col16 = lane & 15, ebase = (lane >> 4)*4;
        for (int p = wid; p < 11; p += 4) {
            f32x4 acc = {0.f, 0.f, 0.f, 0.f};
            if (p < 6) {
                int i = p >> 1, nt = p & 1;
                #pragma unroll
                for (int ks = 0; ks < 2; ks++) {
                    bf16x8 a = *(const bf16x8*)(aV1r + ((i*2 + ks)*64 + lane)*8);
                    bf16x8 b = *(const bf16x8*)(wsb + OFF_W1 + ((nt*2 + ks)*64 + lane)*8);
                    acc = __builtin_amdgcn_mfma_f32_16x16x32_bf16(a, b, acc, 0, 0, 0);
                }
                int col = nt*16 + col16;
                #pragma unroll
                for (int r = 0; r < 4; r++) v1m[(i*16 + ebase + r)*33 + col] = (__bf16)acc[r];
            } else {
                int i = p - 6;
                bf16x8 a = *(const bf16x8*)(aV2r + (i*64 + lane)*8);
                bf16x8 b = *(const bf16x8*)(wsb + OFF_W2 + lane*8);
                acc = __builtin_amdgcn_mfma_f32_16x16x32_bf16(a, b, acc, 0, 0, 0);
                #pragma unroll
                for (int r = 0; r < 4; r++) v2m[(i*16 + ebase + r)*17 + col16] = (__bf16)acc[r];
            }
        }
    }
    __syncthreads();

    // ---- T3a: s_act A-frag + gates ----
    if (t < 128) {
        int ks = t >> 6, l2 = t & 63, e = l2 & 15, o0 = ks*32 + (l2 >> 4)*8;
        bf16x8 v;
        #pragma unroll
        for (int j = 0; j < 8; j++) {
            int o = o0 + j;
            float x = (float)Cb[e*392 + 272 + o] * (float)Cb[e*392 + o];
            v[j] = (__bf16)(x * sigf(x));
        }
        *(bf16x8*)(aSact + t*8) = v;
    }
    for (int idx = t; idx < 768; idx += 256) {
        int e = idx / 48, o = idx - e*48;
        float x = (float)Cb[e*392 + 336 + o] * (float)Cb[e*392 + 64 + o];
        gts[e*49 + o] = sigf(x);
    }
    __syncthreads();

    // ---- T3b: scale + rotate-back + gate -> A-frags ----
    for (int idx = t; idx < 512; idx += 256) {
        if (idx < 192) {
            int i = idx >> 6, l2 = idx & 63, e = l2 & 15, c0 = (l2 >> 4)*8;
            float d0 = d1s[e*9 + i*3], d1 = d1s[e*9 + i*3 + 1], d2 = d1s[e*9 + i*3 + 2];
            bf16x8 v;
            #pragma unroll
            for (int j = 0; j < 8; j++) {
                int c = c0 + j;
                float scl = (float)Cb[e*392 + 112 + c];
                float g   = gts[e*49 + c];
                float m0 = (float)v1m[e*33 + c], m1 = (float)v1m[(16 + e)*33 + c],
                      m2 = (float)v1m[(32 + e)*33 + c];
                v[j] = (__bf16)(g * scl * (d0*m0 + d1*m1 + d2*m2));
            }
            *(bf16x8*)(aV1g + idx*8) = v;
        } else {
            int idx2 = idx - 192;
            int i = idx2 >> 6, l2 = idx2 & 63, e = l2 & 15, c0 = (l2 >> 4)*8;
            const float* dd = d2s + e*25 + i*5;
            bf16x8 v;
            #pragma unroll
            for (int j = 0; j < 8; j++) {
                int c = c0 + j;
                float val = 0.f;
                if (c < 16) {
                    float scl = (float)Cb[e*392 + 144 + c];
                    float g   = gts[e*49 + 32 + c];
                    float acc = 0.f;
                    #pragma unroll
                    for (int z = 0; z < 5; z++) acc += dd[z] * (float)v2m[(z*16 + e)*17 + c];
                    val = g * scl * acc;
                }
                v[j] = (__bf16)val;
            }
            *(bf16x8*)(aV2g + idx2*8) = v;
        }
    }
    __syncthreads();

    // ---- T4: post GEMMs, env scale, atomic scatter ----
    {
        int col16 = lane & 15, ebase = (lane >> 4)*4;
        for (int p = wid; p < 15; p += 4) {
            f32x4 acc = {0.f, 0.f, 0.f, 0.f};
            if (p < 4) {
                int nt = p;
                #pragma unroll
                for (int ks = 0; ks < 2; ks++) {
                    bf16x8 a = *(const bf16x8*)(aSact + (ks*64 + lane)*8);
                    bf16x8 b = *(const bf16x8*)(wsb + OFF_PW0 + ((nt*2 + ks)*64 + lane)*8);
                    acc = __builtin_amdgcn_mfma_f32_16x16x32_bf16(a, b, acc, 0, 0, 0);
                }
                int o = nt*16 + col16;
                float bias = pb0[o];
                #pragma unroll
                for (int r = 0; r < 4; r++) {
                    int e = ebase + r;
                    float val = (acc[r] + bias) * (float)Cb[e*392 + 160 + o];
                    atomicAdd(agg + srcs[e]*240 + o, val);
                }
            } else if (p < 10) {
                int q = p - 4, i = q >> 1, nt = q & 1;
                bf16x8 a = *(const bf16x8*)(aV1g + (i*64 + lane)*8);
                bf16x8 b = *(const bf16x8*)(wsb + OFF_PW1 + (nt*64 + lane)*8);
                acc = __builtin_amdgcn_mfma_f32_16x16x32_bf16(a, b, acc, 0, 0, 0);
                int o = nt*16 + col16;
                #pragma unroll
                for (int r = 0; r < 4; r++) {
                    int e = ebase + r;
                    float val = acc[r] * (float)Cb[e*392 + 224 + o];
                    atomicAdd(agg + srcs[e]*240 + 64 + o*3 + i, val);
                }
            } else {
                int i = p - 10;
                bf16x8 a = *(const bf16x8*)(aV2g + (i*64 + lane)*8);
                bf16x8 b = *(const bf16x8*)(wsb + OFF_PW2 + lane*8);
                acc = __builtin_amdgcn_mfma_f32_16x16x32_bf16(a, b, acc, 0, 0, 0);
                #pragma unroll
                for (int r = 0; r < 4; r++) {
                    int e = ebase + r;
                    float val = acc[r] * (float)Cb[e*392 + 256 + col16];
                    atomicAdd(agg + srcs[e]*240 + 160 + col16*5 + i, val);
                }
            }
        }
    }
}

// ---------------------------------------------------------------------------
// Node kernel: 16 nodes/block, 2 col-groups x 128; each thread does 8 nodes
// per weight load (8x ILP on the L2 latency chain).
// ---------------------------------------------------------------------------
__global__ __launch_bounds__(256, 2) void node_kernel(
    const float* __restrict__ nf, const float* __restrict__ mcplg,
    const float* __restrict__ ohg,
    const float* __restrict__ cW1, const float* __restrict__ cb1,
    const float* __restrict__ cW2, const float* __restrict__ cb2,
    const float* __restrict__ gsW, const float* __restrict__ gsb,
    const float* __restrict__ mW1, const float* __restrict__ mb1,
    const float* __restrict__ mW2, const float* __restrict__ mb2,
    const float* __restrict__ lng, const float* __restrict__ lnb,
    const float* __restrict__ rW0, const float* __restrict__ rb0,
    const float* __restrict__ rW1, const float* __restrict__ rW2,
    const float* __restrict__ ohT, float* out0, float* out1)
{
    __shared__ __align__(16) unsigned char pool[68608];
    float* mcp  = (float*)(pool + 0);      // [16][128]
    float* ohv  = (float*)(pool + 8192);   // [16][96]  (padded K)
    float* nsr  = (float*)(pool + 14336);  // [16][240]
    float* anew = (float*)(pool + 29696);  // [16][240]
    float* t12  = (float*)(pool + 45056);  // [16][128] t1 then t2
    float* cfg  = (float*)(pool + 53248);  // [16][112] coeffs then gv
    float* scm  = (float*)(pool + 60416);  // [16][128] scal then mcn

    const int t  = threadIdx.x;
    const int g  = t >> 7;        // wave-uniform (waves 0,1 -> g=0; 2,3 -> g=1)
    const int o  = t & 127;
    const int nb = g * 8;
    const int n0 = blockIdx.x * NPB;

    for (int idx = t; idx < NPB * 128; idx += 256) {
        int n = idx >> 7, k = idx & 127;
        mcp[n*128 + k] = mcplg[(n0 + n) * 128 + k];
    }
    for (int idx = t; idx < NPB * 96; idx += 256) {
        int n = idx / 96, k = idx - n * 96;
        ohv[n*96 + k] = (k < 95) ? ohg[(n0 + n) * 95 + k] : 0.f;
    }
    for (int idx = t; idx < NPB * 240; idx += 256) {
        int n = idx / 240, k = idx - n * 240;
        nsr[n*240 + k]  = nf[(n0 + n) * DIM + k];
        anew[n*240 + k] = out0[(n0 + n) * DIM + k];   // agg (atomic sums)
    }
    __syncthreads();

    // t1 = silu(mcp @ cW1 + cb1)
    {
        float a[8]; float b = cb1[o];
        #pragma unroll
        for (int i = 0; i < 8; i++) a[i] = b;
        #pragma unroll 2
        for (int k4 = 0; k4 < 32; k4++) {
            float w0 = cW1[(4*k4+0)*128 + o], w1 = cW1[(4*k4+1)*128 + o],
                  w2 = cW1[(4*k4+2)*128 + o], w3 = cW1[(4*k4+3)*128 + o];
            #pragma unroll
            for (int i = 0; i < 8; i++) {
                float4 m = *(const float4*)&mcp[(nb+i)*128 + 4*k4];
                a[i] += m.x*w0 + m.y*w1 + m.z*w2 + m.w*w3;
            }
        }
        #pragma unroll
        for (int i = 0; i < 8; i++) { float x = a[i]; t12[(nb+i)*128 + o] = x * sigf(x); }
    }
    __syncthreads();

    // coeffs = t1 @ cW2 + cb2
    if (o < 112) {
        float a[8]; float b = cb2[o];
        #pragma unroll
        for (int i = 0; i < 8; i++) a[i] = b;
        #pragma unroll 2
        for (int k4 = 0; k4 < 32; k4++) {
            float w0 = cW2[(4*k4+0)*112 + o], w1 = cW2[(4*k4+1)*112 + o],
                  w2 = cW2[(4*k4+2)*112 + o], w3 = cW2[(4*k4+3)*112 + o];
            #pragma unroll
            for (int i = 0; i < 8; i++) {
                float4 m = *(const float4*)&t12[(nb+i)*128 + 4*k4];
                a[i] += m.x*w0 + m.y*w1 + m.z*w2 + m.w*w3;
            }
        }
        #pragma unroll
        for (int i = 0; i < 8; i++) cfg[(nb+i)*112 + o] = a[i];
    }
    __syncthreads();

    // new_nf = agg * AVG_NEI^-0.5 * coeffs[SCALE_IDX]
    for (int idx = t; idx < NPB * 240; idx += 256) {
        int n = idx / 240, d = idx - n * 240;
        int ch = (d < 64) ? d : (d < 160 ? 64 + (d - 64) / 3 : 96 + (d - 160) / 5);
        anew[n*240 + d] *= 0.25f * cfg[n*112 + ch];
    }
    __syncthreads();

    // scal = new_nf[:,:64] @ gsW + gsb
    {
        float a[8]; float b = gsb[o];
        #pragma unroll
        for (int i = 0; i < 8; i++) a[i] = b;
        #pragma unroll 2
        for (int k4 = 0; k4 < 16; k4++) {
            float w0 = gsW[(4*k4+0)*128 + o], w1 = gsW[(4*k4+1)*128 + o],
                  w2 = gsW[(4*k4+2)*128 + o], w3 = gsW[(4*k4+3)*128 + o];
            #pragma unroll
            for (int i = 0; i < 8; i++) {
                float4 m = *(const float4*)&anew[(nb+i)*240 + 4*k4];
                a[i] += m.x*w0 + m.y*w1 + m.z*w2 + m.w*w3;
            }
        }
        #pragma unroll
        for (int i = 0; i < 8; i++) scm[(nb+i)*128 + o] = a[i];
    }
    __syncthreads();

    // t2 = silu([scal, mcp] @ mW1 + mb1)
    {
        float a[8]; float b = mb1[o];
        #pragma unroll
        for (int i = 0; i < 8; i++) a[i] = b;
        #pragma unroll 2
        for (int k4 = 0; k4 < 32; k4++) {
            float w0 = mW1[(4*k4+0)*128 + o], w1 = mW1[(4*k4+1)*128 + o],
                  w2 = mW1[(4*k4+2)*128 + o], w3 = mW1[(4*k4+3)*128 + o];
            #pragma unroll
            for (int i = 0; i < 8; i++) {
                float4 m = *(const float4*)&scm[(nb+i)*128 + 4*k4];
                a[i] += m.x*w0 + m.y*w1 + m.z*w2 + m.w*w3;
            }
        }
        #pragma unroll 2
        for (int k4 = 0; k4 < 32; k4++) {
            float w0 = mW1[(128+4*k4+0)*128 + o], w1 = mW1[(128+4*k4+1)*128 + o],
                  w2 = mW1[(128+4*k4+2)*128 + o], w3 = mW1[(128+4*k4+3)*128 + o];
            #pragma unroll
            for (int i = 0; i < 8; i++) {
                float4 m = *(const float4*)&mcp[(nb+i)*128 + 4*k4];
                a[i] += m.x*w0 + m.y*w1 + m.z*w2 + m.w*w3;
            }
        }
        #pragma unroll
        for (int i = 0; i < 8; i++) { float x = a[i]; t12[(nb+i)*128 + o] = x * sigf(x); }
    }
    __syncthreads();

    // mcn = mcp + t2 @ mW2 + mb2  -> scm
    {
        float a[8]; float b = mb2[o];
        #pragma unroll
        for (int i = 0; i < 8; i++) a[i] = b;
        #pragma unroll 2
        for (int k4 = 0; k4 < 32; k4++) {
            float w0 = mW2[(4*k4+0)*128 + o], w1 = mW2[(4*k4+1)*128 + o],
                  w2 = mW2[(4*k4+2)*128 + o], w3 = mW2[(4*k4+3)*128 + o];
            #pragma unroll
            for (int i = 0; i < 8; i++) {
                float4 m = *(const float4*)&t12[(nb+i)*128 + 4*k4];
                a[i] += m.x*w0 + m.y*w1 + m.z*w2 + m.w*w3;
            }
        }
        #pragma unroll
        for (int i = 0; i < 8; i++) scm[(nb+i)*128 + o] = mcp[(nb+i)*128 + o] + a[i];
    }
    __syncthreads();

    // LayerNorm: 16-lane group per node
    {
        int n = t >> 4, l = t & 15;
        float x[8]; float s = 0.f, ss = 0.f;
        #pragma unroll
        for (int i = 0; i < 8; i++) { x[i] = scm[n*128 + l + 16*i]; s += x[i]; ss += x[i]*x[i]; }
        #pragma unroll
        for (int off = 8; off > 0; off >>= 1) {
            s  += __shfl_down(s,  off, 16);
            ss += __shfl_down(ss, off, 16);
        }
        s  = __shfl(s, 0, 16);
        ss = __shfl(ss, 0, 16);
        float mu   = s * (1.f / 128.f);
        float var  = ss * (1.f / 128.f) - mu * mu;
        float rstd = rsqrtf(var + 1e-5f);
        float* op = out1 + (n0 + n) * 128;
        #pragma unroll
        for (int i = 0; i < 8; i++) {
            int c = l + 16*i;
            op[c] = (x[i] - mu) * rstd * lng[c] + lnb[c];
        }
    }

    // gv = ohv @ ohT (scale folded in) -> cfg
    if (o < 112) {
        float a[8] = {0.f,0.f,0.f,0.f,0.f,0.f,0.f,0.f};
        #pragma unroll 2
        for (int k4 = 0; k4 < 24; k4++) {
            float w0 = ohT[(4*k4+0)*112 + o], w1 = ohT[(4*k4+1)*112 + o],
                  w2 = ohT[(4*k4+2)*112 + o], w3 = ohT[(4*k4+3)*112 + o];
            #pragma unroll
            for (int i = 0; i < 8; i++) {
                float4 m = *(const float4*)&ohv[(nb+i)*96 + 4*k4];
                a[i] += m.x*w0 + m.y*w1 + m.z*w2 + m.w*w3;
            }
        }
        #pragma unroll
        for (int i = 0; i < 8; i++) cfg[(nb+i)*112 + o] = a[i];
    }
    __syncthreads();

    // residual + combine + one-hot gain
    const float c_new = 0.4472135955f;   // sigmoid(0)*rsqrt(1.25)
    const float c_old = 0.8944271910f;   // rsqrt(1.25)
    for (int idx = t; idx < NPB * 240; idx += 256) {
        int n = idx / 240, d = idx - n * 240;
        float res, gg;
        if (d < 64) {
            float acc = rb0[d];
            #pragma unroll 4
            for (int c = 0; c < 64; c++) acc += nsr[n*240 + c] * rW0[c * 64 + d];
            res = acc; gg = cfg[n*112 + d];
        } else if (d < 160) {
            int dd = d - 64, oo = dd / 3, j = dd - oo * 3;
            float acc = 0.f;
            #pragma unroll 4
            for (int c = 0; c < 32; c++) acc += nsr[n*240 + 64 + c*3 + j] * rW1[c * 32 + oo];
            res = acc; gg = cfg[n*112 + 64 + oo];
        } else {
            int dd = d - 160, oo = dd / 5, j = dd - oo * 5;
            float acc = 0.f;
            #pragma unroll 4
            for (int c = 0; c < 16; c++) acc += nsr[n*240 + 160 + c*5 + j] * rW2[c * 16 + oo];
            res = acc; gg = cfg[n*112 + 96 + oo];
        }
        float v = c_new * anew[n*240 + d] + c_old * res;
        out0[(n0 + n) * DIM + d] = v * (1.f + gg);
    }
}

extern "C" void kernel_launch(void* const* d_in, const int* in_sizes, int n_in,
                              void* d_out, int out_size, void* d_ws, size_t ws_size,
                              hipStream_t stream) {
    const float* nf      = (const float*)d_in[0];
    const float* ef      = (const float*)d_in[1];
    const float* lat     = (const float*)d_in[2];
    const float* mcpl    = (const float*)d_in[3];
    const float* ohot    = (const float*)d_in[4];
    const float* D1      = (const float*)d_in[5];
    const float* D2      = (const float*)d_in[6];
    const float* so2_W0  = (const float*)d_in[7];
    const float* so2_W1  = (const float*)d_in[8];
    const float* so2_W2  = (const float*)d_in[9];
    const float* so2_Ws  = (const float*)d_in[10];
    const float* env_W   = (const float*)d_in[11];
    const float* post_W0 = (const float*)d_in[12];
    const float* post_b0 = (const float*)d_in[13];
    const float* post_W1 = (const float*)d_in[14];
    const float* post_W2 = (const float*)d_in[15];
    const float* res_W0  = (const float*)d_in[16];
    const float* res_b0  = (const float*)d_in[17];
    const float* res_W1  = (const float*)d_in[18];
    const float* res_W2  = (const float*)d_in[19];
    const float* cpl_W1  = (const float*)d_in[20];
    const float* cpl_b1  = (const float*)d_in[21];
    const float* cpl_W2  = (const float*)d_in[22];
    const float* cpl_b2  = (const float*)d_in[23];
    const float* gs_W    = (const float*)d_in[24];
    const float* gs_b    = (const float*)d_in[25];
    const float* msg_W1  = (const float*)d_in[26];
    const float* msg_b1  = (const float*)d_in[27];
    const float* msg_W2  = (const float*)d_in[28];
    const float* msg_b2  = (const float*)d_in[29];
    const float* ln_g    = (const float*)d_in[30];
    const float* ln_b    = (const float*)d_in[31];
    const float* oh_w0   = (const float*)d_in[32];
    const float* oh_w1   = (const float*)d_in[33];
    const float* oh_w2   = (const float*)d_in[34];
    const int*   eidx    = (const int*)d_in[35];   // (2,E); row 0 = src

    float* out0 = (float*)d_out;                     // N*DIM, doubles as agg
    float* out1 = (float*)d_out + (size_t)NN * DIM;  // N*CPL
    __bf16* wsb = (__bf16*)d_ws;
    float*  ohT = (float*)((char*)d_ws + OHT_BYTE_OFF);

    (void)hipMemsetAsync(out0, 0, (size_t)NN * DIM * sizeof(float), stream);

    prep_kernel<<<56, 256, 0, stream>>>(so2_Ws, env_W, so2_W0, so2_W1, so2_W2,
                                        post_W0, post_W1, post_W2,
                                        oh_w0, oh_w1, oh_w2, wsb, ohT);

    edge_mfma_kernel<<<NE / EB, 256, 0, stream>>>(
        nf, ef, lat, D1, D2, post_b0, eidx, wsb, out0);

    node_kernel<<<NN / NPB, 256, 0, stream>>>(
        nf, mcpl, ohot, cpl_W1, cpl_b1, cpl_W2, cpl_b2, gs_W, gs_b,
        msg_W1, msg_b1, msg_W2, msg_b2, ln_g, ln_b,
        res_W0, res_b0, res_W1, res_W2, ohT, out0, out1);
}

// Round 6
// 751.610 us; speedup vs baseline: 2.7864x; 1.1792x over previous
//
#include <hip/hip_runtime.h>

#define NN   10000
#define NE   160000
#define DIM  240
#define EB   16    // edges per block (edge kernel)
#define NPB  16    // nodes per block (node kernel)

typedef __bf16 bf16x8 __attribute__((ext_vector_type(8)));
typedef __bf16 bf16x4 __attribute__((ext_vector_type(4)));
typedef float  f32x4  __attribute__((ext_vector_type(4)));

__device__ __forceinline__ float sigf(float x) { return 1.0f / (1.0f + __expf(-x)); }

// -------- workspace layout --------
// bf16 B-fragments for mfma_f32_16x16x32_bf16:
//   lane l holds B[k=(l>>4)*8+j][n=l&15], j=0..7, per (nt, ks)
#define OFF_WB1 0        // [Ws|We]: N=272 (17 nt), K=128 (4 ks)
#define OFF_WB2 34816    // W0:      N=112 (7 nt),  K=128 (4 ks)
#define OFF_W1  49152    // so2_W1:  N=32 (2 nt),   K=64  (2 ks)
#define OFF_W2  51200    // so2_W2:  N=16 (1 nt),   K=32  (1 ks)
#define OFF_PW0 51712    // post_W0: N=64 (4 nt),   K=64  (2 ks)
#define OFF_PW1 55808    // post_W1: N=32 (2 nt),   K=32  (1 ks)
#define OFF_PW2 56832    // post_W2: N=16 (1 nt),   K=16 pad 32
#define OHT_BYTE_OFF 131072     // float [96][112]
#define CNT_BYTE_OFF 196608     // int [10240]
#define ROW_BYTE_OFF 237568     // int [10016] (rowptr, 10001 used)
#define CUR_BYTE_OFF 282624     // int [10240]
#define EID_BYTE_OFF 327680     // int [160000]
#define MSG_BYTE_OFF 1048576    // bf16 [NE][240] = 76.8 MB

__global__ __launch_bounds__(256) void prep_kernel(
    const float* __restrict__ Ws, const float* __restrict__ We, const float* __restrict__ W0,
    const float* __restrict__ W1, const float* __restrict__ W2,
    const float* __restrict__ pW0, const float* __restrict__ pW1, const float* __restrict__ pW2,
    const float* __restrict__ w0g, const float* __restrict__ w1g, const float* __restrict__ w2g,
    __bf16* __restrict__ wsb, float* __restrict__ ohT)
{
    int tid = blockIdx.x * 256 + threadIdx.x;
    int stride = gridDim.x * 256;
    for (int idx = tid; idx < 17*4*512; idx += stride) {
        int j = idx & 7, lane = (idx >> 3) & 63, ks = (idx >> 9) & 3, nt = idx >> 11;
        int k = ks*32 + (lane >> 4)*8 + j, n = nt*16 + (lane & 15);
        float v = (n < 160) ? Ws[k*160 + n] : We[k*112 + (n - 160)];
        wsb[OFF_WB1 + idx] = (__bf16)v;
    }
    for (int idx = tid; idx < 7*4*512; idx += stride) {
        int j = idx & 7, lane = (idx >> 3) & 63, ks = (idx >> 9) & 3, nt = idx >> 11;
        int k = ks*32 + (lane >> 4)*8 + j, n = nt*16 + (lane & 15);
        wsb[OFF_WB2 + idx] = (__bf16)W0[k*112 + n];
    }
    for (int idx = tid; idx < 2*2*512; idx += stride) {
        int j = idx & 7, lane = (idx >> 3) & 63, ks = (idx >> 9) & 1, nt = idx >> 10;
        int k = ks*32 + (lane >> 4)*8 + j, n = nt*16 + (lane & 15);
        wsb[OFF_W1 + idx] = (__bf16)W1[k*32 + n];
    }
    for (int idx = tid; idx < 512; idx += stride) {
        int j = idx & 7, lane = (idx >> 3) & 63;
        int k = (lane >> 4)*8 + j, n = lane & 15;
        wsb[OFF_W2 + idx] = (__bf16)W2[k*16 + n];
    }
    for (int idx = tid; idx < 4*2*512; idx += stride) {
        int j = idx & 7, lane = (idx >> 3) & 63, ks = (idx >> 9) & 1, nt = idx >> 10;
        int k = ks*32 + (lane >> 4)*8 + j, n = nt*16 + (lane & 15);
        wsb[OFF_PW0 + idx] = (__bf16)pW0[k*64 + n];
    }
    for (int idx = tid; idx < 2*512; idx += stride) {
        int j = idx & 7, lane = (idx >> 3) & 63, nt = idx >> 9;
        int k = (lane >> 4)*8 + j, n = nt*16 + (lane & 15);
        wsb[OFF_PW1 + idx] = (__bf16)pW1[k*32 + n];
    }
    for (int idx = tid; idx < 512; idx += stride) {
        int j = idx & 7, lane = (idx >> 3) & 63;
        int k = (lane >> 4)*8 + j, n = lane & 15;
        wsb[OFF_PW2 + idx] = (k < 16) ? (__bf16)pW2[k*16 + n] : (__bf16)0.0f;
    }
    for (int idx = tid; idx < 96*112; idx += stride) {
        int k = idx / 112, n2 = idx - k*112;
        float v = 0.f;
        if (k < 95) {
            if (n2 < 64)      v = w0g[n2*95 + k];
            else if (n2 < 96) v = w1g[(n2-64)*95 + k];
            else              v = w2g[(n2-96)*95 + k];
        }
        ohT[idx] = v * 0.10259783521f;
    }
}

// ---------------- CSR build ----------------
__global__ __launch_bounds__(256) void count_kernel(const int* __restrict__ src, int* __restrict__ cnt) {
    int e = blockIdx.x * 256 + threadIdx.x;
    if (e < NE) atomicAdd(&cnt[src[e]], 1);
}

__global__ __launch_bounds__(256) void scan_kernel(const int* __restrict__ cnt,
                                                   int* __restrict__ rowptr, int* __restrict__ cur) {
    __shared__ int part[256];
    int t = threadIdx.x;
    int base = t * 40;
    int local[40];
    int s = 0;
    #pragma unroll
    for (int i = 0; i < 40; i++) {
        int idx = base + i;
        int v = (idx < NN) ? cnt[idx] : 0;
        local[i] = s; s += v;
    }
    part[t] = s;
    __syncthreads();
    for (int off = 1; off < 256; off <<= 1) {
        int v = (t >= off) ? part[t - off] : 0;
        __syncthreads();
        part[t] += v;
        __syncthreads();
    }
    int pre = (t > 0) ? part[t - 1] : 0;
    #pragma unroll
    for (int i = 0; i < 40; i++) {
        int idx = base + i;
        if (idx < NN) { int r = pre + local[i]; rowptr[idx] = r; cur[idx] = r; }
    }
    if (t == 255) rowptr[NN] = part[255];
}

__global__ __launch_bounds__(256) void fill_kernel(const int* __restrict__ src,
                                                   int* __restrict__ cur, int* __restrict__ eidl) {
    int e = blockIdx.x * 256 + threadIdx.x;
    if (e < NE) {
        int slot = atomicAdd(&cur[src[e]], 1);
        eidl[slot] = e;
    }
}

// ---------------- aggregation: gather messages per node ----------------
__global__ __launch_bounds__(256) void agg_kernel(
    const __bf16* __restrict__ msg, const int* __restrict__ rowptr,
    const int* __restrict__ eidl, float* __restrict__ out0)
{
    int wid = threadIdx.x >> 6, lane = threadIdx.x & 63;
    int node = blockIdx.x * 4 + wid;
    if (node >= NN || lane >= 60) return;
    int beg = rowptr[node], end = rowptr[node + 1];
    float a0 = 0.f, a1 = 0.f, a2 = 0.f, a3 = 0.f;
    int i = beg;
    for (; i + 4 <= end; i += 4) {
        int e0 = eidl[i], e1 = eidl[i+1], e2 = eidl[i+2], e3 = eidl[i+3];
        bf16x4 v0 = *(const bf16x4*)(msg + (size_t)e0*240 + lane*4);
        bf16x4 v1 = *(const bf16x4*)(msg + (size_t)e1*240 + lane*4);
        bf16x4 v2 = *(const bf16x4*)(msg + (size_t)e2*240 + lane*4);
        bf16x4 v3 = *(const bf16x4*)(msg + (size_t)e3*240 + lane*4);
        a0 += (float)v0[0] + (float)v1[0] + (float)v2[0] + (float)v3[0];
        a1 += (float)v0[1] + (float)v1[1] + (float)v2[1] + (float)v3[1];
        a2 += (float)v0[2] + (float)v1[2] + (float)v2[2] + (float)v3[2];
        a3 += (float)v0[3] + (float)v1[3] + (float)v2[3] + (float)v3[3];
    }
    for (; i < end; i++) {
        int e = eidl[i];
        bf16x4 v = *(const bf16x4*)(msg + (size_t)e*240 + lane*4);
        a0 += (float)v[0]; a1 += (float)v[1]; a2 += (float)v[2]; a3 += (float)v[3];
    }
    float4 r = { a0, a1, a2, a3 };
    *(float4*)(out0 + (size_t)node*240 + lane*4) = r;
}

// ---------------------------------------------------------------------------
// Edge kernel (MFMA): 16 edges/block, 256 threads, 36.5 KB LDS -> 4 blocks/CU
// msgout != nullptr: write bf16 messages (no atomics). else: atomic scatter.
// ---------------------------------------------------------------------------
__global__ __launch_bounds__(256, 4) void edge_mfma_kernel(
    const float* __restrict__ nf, const float* __restrict__ ef,
    const float* __restrict__ latg, const float* __restrict__ D1g, const float* __restrict__ D2g,
    const float* __restrict__ pb0, const int* __restrict__ srcg,
    const __bf16* __restrict__ wsb, float* agg, __bf16* __restrict__ msgout)
{
    __shared__ __align__(16) unsigned char pool[37376];
    __bf16* Cb   = (__bf16*)(pool + 0);       // [16][392] (after T1)
    __bf16* vst  = (__bf16*)(pool + 0);       // [16][360] (T0 only, alias)
    __bf16* aLat = (__bf16*)(pool + 12544);   // [4][64][8]   dead after T1
    __bf16* aSin = (__bf16*)(pool + 16640);   // [4][64][8]   dead after T1
    __bf16* v1m  = (__bf16*)(pool + 12544);   // [48][33]     alias, from T2
    __bf16* v2m  = (__bf16*)(pool + 15712);   // [80][17]     alias, from T2
    __bf16* aV1r = (__bf16*)(pool + 20736);   // [6][64][8]   dead after T2
    __bf16* aV2r = (__bf16*)(pool + 26880);   // [5][64][8]   dead after T2
    __bf16* aSact= (__bf16*)(pool + 20736);   // [2][64][8]   alias, from T3
    __bf16* aV1g = (__bf16*)(pool + 22784);   // [3][64][8]
    __bf16* aV2g = (__bf16*)(pool + 25856);   // [5][64][8]
    float*  d1s  = (float*)(pool + 32000);    // [16*9]
    float*  d2s  = (float*)(pool + 32576);    // [16*25]
    float*  gts  = (float*)(pool + 34176);    // [16][49]
    int*    srcs = (int*)  (pool + 37312);    // [16]

    const int t    = threadIdx.x;
    const int wid  = t >> 6, lane = t & 63;
    const int e0   = blockIdx.x * EB;

    if (t < 16) srcs[t] = srcg[e0 + t];
    __syncthreads();

    // ---- T0: staging ----
    for (int idx = t; idx < 144; idx += 256) d1s[idx] = D1g[e0*9  + idx];
    for (int idx = t; idx < 400; idx += 256) d2s[idx] = D2g[e0*25 + idx];
    for (int idx = t; idx < 16*88; idx += 256) {
        int e = idx / 88, c4 = idx - e*88;
        const float4* p = (c4 < 44) ? (const float4*)(nf + srcs[e]*240 + 64 + c4*4)
                                    : (const float4*)(ef + (e0 + e)*240 + 64 + (c4 - 44)*4);
        float4 f = *p;
        bf16x4 v = { (__bf16)f.x, (__bf16)f.y, (__bf16)f.z, (__bf16)f.w };
        *(bf16x4*)(vst + e*360 + c4*4) = v;
    }
    {
        int ks = t >> 6, l2 = t & 63, e = l2 & 15, q = l2 >> 4;
        int k0 = ks*32 + q*8;
        {
            const float4* p4 = (const float4*)(latg + (e0 + e)*128 + k0);
            float4 f0 = p4[0], f1 = p4[1];
            bf16x8 v;
            v[0]=(__bf16)f0.x; v[1]=(__bf16)f0.y; v[2]=(__bf16)f0.z; v[3]=(__bf16)f0.w;
            v[4]=(__bf16)f1.x; v[5]=(__bf16)f1.y; v[6]=(__bf16)f1.z; v[7]=(__bf16)f1.w;
            *(bf16x8*)(aLat + t*8) = v;
        }
        {
            const float* s2 = (k0 < 64) ? (nf + srcs[e]*240 + k0)
                                        : (ef + (e0 + e)*240 + (k0 - 64));
            const float4* p4 = (const float4*)s2;
            float4 f0 = p4[0], f1 = p4[1];
            bf16x8 v;
            v[0]=(__bf16)f0.x; v[1]=(__bf16)f0.y; v[2]=(__bf16)f0.z; v[3]=(__bf16)f0.w;
            v[4]=(__bf16)f1.x; v[5]=(__bf16)f1.y; v[6]=(__bf16)f1.z; v[7]=(__bf16)f1.w;
            *(bf16x8*)(aSin + t*8) = v;
        }
    }
    __syncthreads();

    // ---- T0b: rotated A-fragments from LDS ----
    for (int idx = t; idx < 384; idx += 256) {
        int i = idx >> 7, rem = idx & 127, ks = rem >> 6, l2 = rem & 63;
        int e = l2 & 15, q = l2 >> 4;
        int c0 = ks*32 + q*8;
        float da = d1s[e*9 + i*3 + 0], db = d1s[e*9 + i*3 + 1], dc = d1s[e*9 + i*3 + 2];
        const __bf16* ve = vst + e*360;
        bf16x8 v;
        #pragma unroll
        for (int j = 0; j < 8; j++) {
            int c = c0 + j;
            const __bf16* p = (c < 32) ? (ve + c*3) : (ve + 176 + (c - 32)*3);
            v[j] = (__bf16)(da*(float)p[0] + db*(float)p[1] + dc*(float)p[2]);
        }
        *(bf16x8*)(aV1r + idx*8) = v;
    }
    for (int idx = t; idx < 320; idx += 256) {
        int i = idx >> 6, l2 = idx & 63, e = l2 & 15, q = l2 >> 4;
        int c0 = q*8;
        const float* dd = d2s + e*25 + i*5;
        const __bf16* ve = vst + e*360;
        bf16x8 v;
        #pragma unroll
        for (int j = 0; j < 8; j++) {
            int c = c0 + j;
            const __bf16* p = (c < 16) ? (ve + 96 + c*5) : (ve + 272 + (c - 16)*5);
            float a = 0.f;
            #pragma unroll
            for (int z = 0; z < 5; z++) a += dd[z]*(float)p[z];
            v[j] = (__bf16)a;
        }
        *(bf16x8*)(aV2r + idx*8) = v;
    }
    __syncthreads();   // vst dead; Cb region live from here

    // ---- T1: GEMM1 ----
    {
        int col16 = lane & 15, ebase = (lane >> 4)*4;
        bf16x8 aL[4], aS[4];
        #pragma unroll
        for (int ks = 0; ks < 4; ks++) {
            aL[ks] = *(const bf16x8*)(aLat + (ks*64 + lane)*8);
            aS[ks] = *(const bf16x8*)(aSin + (ks*64 + lane)*8);
        }
        #pragma unroll
        for (int it = 0; it < 6; it++) {
            int nt = wid + it*4;
            bool isLat = nt < 17;
            const __bf16* bB = isLat ? (wsb + OFF_WB1 + nt*2048)
                                     : (wsb + OFF_WB2 + (nt - 17)*2048);
            f32x4 acc = {0.f, 0.f, 0.f, 0.f};
            #pragma unroll
            for (int ks = 0; ks < 4; ks++) {
                bf16x8 b = *(const bf16x8*)(bB + (ks*64 + lane)*8);
                acc = __builtin_amdgcn_mfma_f32_16x16x32_bf16(isLat ? aL[ks] : aS[ks], b, acc, 0, 0, 0);
            }
            int col = (isLat ? nt*16 : 272 + (nt - 17)*16) + col16;
            #pragma unroll
            for (int r = 0; r < 4; r++) Cb[(ebase + r)*392 + col] = (__bf16)acc[r];
        }
    }
    __syncthreads();

    // ---- T2: v1_m raw (3 x 2 nt), v2_m raw (5) ----
    {
        int col16 = lane & 15, ebase = (lane >> 4)*4;
        for (int p = wid; p < 11; p += 4) {
            f32x4 acc = {0.f, 0.f, 0.f, 0.f};
            if (p < 6) {
                int i = p >> 1, nt = p & 1;
                #pragma unroll
                for (int ks = 0; ks < 2; ks++) {
                    bf16x8 a = *(const bf16x8*)(aV1r + ((i*2 + ks)*64 + lane)*8);
                    bf16x8 b = *(const bf16x8*)(wsb + OFF_W1 + ((nt*2 + ks)*64 + lane)*8);
                    acc = __builtin_amdgcn_mfma_f32_16x16x32_bf16(a, b, acc, 0, 0, 0);
                }
                int col = nt*16 + col16;
                #pragma unroll
                for (int r = 0; r < 4; r++) v1m[(i*16 + ebase + r)*33 + col] = (__bf16)acc[r];
            } else {
                int i = p - 6;
                bf16x8 a = *(const bf16x8*)(aV2r + (i*64 + lane)*8);
                bf16x8 b = *(const bf16x8*)(wsb + OFF_W2 + lane*8);
                acc = __builtin_amdgcn_mfma_f32_16x16x32_bf16(a, b, acc, 0, 0, 0);
                #pragma unroll
                for (int r = 0; r < 4; r++) v2m[(i*16 + ebase + r)*17 + col16] = (__bf16)acc[r];
            }
        }
    }
    __syncthreads();

    // ---- T3a: s_act A-frag + gates ----
    if (t < 128) {
        int ks = t >> 6, l2 = t & 63, e = l2 & 15, o0 = ks*32 + (l2 >> 4)*8;
        bf16x8 v;
        #pragma unroll
        for (int j = 0; j < 8; j++) {
            int o = o0 + j;
            float x = (float)Cb[e*392 + 272 + o] * (float)Cb[e*392 + o];
            v[j] = (__bf16)(x * sigf(x));
        }
        *(bf16x8*)(aSact + t*8) = v;
    }
    for (int idx = t; idx < 768; idx += 256) {
        int e = idx / 48, o = idx - e*48;
        float x = (float)Cb[e*392 + 336 + o] * (float)Cb[e*392 + 64 + o];
        gts[e*49 + o] = sigf(x);
    }
    __syncthreads();

    // ---- T3b: scale + rotate-back + gate -> A-frags ----
    for (int idx = t; idx < 512; idx += 256) {
        if (idx < 192) {
            int i = idx >> 6, l2 = idx & 63, e = l2 & 15, c0 = (l2 >> 4)*8;
            float d0 = d1s[e*9 + i*3], d1 = d1s[e*9 + i*3 + 1], d2 = d1s[e*9 + i*3 + 2];
            bf16x8 v;
            #pragma unroll
            for (int j = 0; j < 8; j++) {
                int c = c0 + j;
                float scl = (float)Cb[e*392 + 112 + c];
                float g   = gts[e*49 + c];
                float m0 = (float)v1m[e*33 + c], m1 = (float)v1m[(16 + e)*33 + c],
                      m2 = (float)v1m[(32 + e)*33 + c];
                v[j] = (__bf16)(g * scl * (d0*m0 + d1*m1 + d2*m2));
            }
            *(bf16x8*)(aV1g + idx*8) = v;
        } else {
            int idx2 = idx - 192;
            int i = idx2 >> 6, l2 = idx2 & 63, e = l2 & 15, c0 = (l2 >> 4)*8;
            const float* dd = d2s + e*25 + i*5;
            bf16x8 v;
            #pragma unroll
            for (int j = 0; j < 8; j++) {
                int c = c0 + j;
                float val = 0.f;
                if (c < 16) {
                    float scl = (float)Cb[e*392 + 144 + c];
                    float g   = gts[e*49 + 32 + c];
                    float acc = 0.f;
                    #pragma unroll
                    for (int z = 0; z < 5; z++) acc += dd[z] * (float)v2m[(z*16 + e)*17 + c];
                    val = g * scl * acc;
                }
                v[j] = (__bf16)val;
            }
            *(bf16x8*)(aV2g + idx2*8) = v;
        }
    }
    __syncthreads();

    // ---- T4: post GEMMs, env scale, message write (or atomic fallback) ----
    {
        int col16 = lane & 15, ebase = (lane >> 4)*4;
        for (int p = wid; p < 15; p += 4) {
            f32x4 acc = {0.f, 0.f, 0.f, 0.f};
            if (p < 4) {
                int nt = p;
                #pragma unroll
                for (int ks = 0; ks < 2; ks++) {
                    bf16x8 a = *(const bf16x8*)(aSact + (ks*64 + lane)*8);
                    bf16x8 b = *(const bf16x8*)(wsb + OFF_PW0 + ((nt*2 + ks)*64 + lane)*8);
                    acc = __builtin_amdgcn_mfma_f32_16x16x32_bf16(a, b, acc, 0, 0, 0);
                }
                int o = nt*16 + col16;
                float bias = pb0[o];
                #pragma unroll
                for (int r = 0; r < 4; r++) {
                    int e = ebase + r;
                    float val = (acc[r] + bias) * (float)Cb[e*392 + 160 + o];
                    if (msgout) msgout[(size_t)(e0 + e)*240 + o] = (__bf16)val;
                    else        atomicAdd(agg + srcs[e]*240 + o, val);
                }
            } else if (p < 10) {
                int q = p - 4, i = q >> 1, nt = q & 1;
                bf16x8 a = *(const bf16x8*)(aV1g + (i*64 + lane)*8);
                bf16x8 b = *(const bf16x8*)(wsb + OFF_PW1 + (nt*64 + lane)*8);
                acc = __builtin_amdgcn_mfma_f32_16x16x32_bf16(a, b, acc, 0, 0, 0);
                int o = nt*16 + col16;
                #pragma unroll
                for (int r = 0; r < 4; r++) {
                    int e = ebase + r;
                    float val = acc[r] * (float)Cb[e*392 + 224 + o];
                    if (msgout) msgout[(size_t)(e0 + e)*240 + 64 + o*3 + i] = (__bf16)val;
                    else        atomicAdd(agg + srcs[e]*240 + 64 + o*3 + i, val);
                }
            } else {
                int i = p - 10;
                bf16x8 a = *(const bf16x8*)(aV2g + (i*64 + lane)*8);
                bf16x8 b = *(const bf16x8*)(wsb + OFF_PW2 + lane*8);
                acc = __builtin_amdgcn_mfma_f32_16x16x32_bf16(a, b, acc, 0, 0, 0);
                #pragma unroll
                for (int r = 0; r < 4; r++) {
                    int e = ebase + r;
                    float val = acc[r] * (float)Cb[e*392 + 256 + col16];
                    if (msgout) msgout[(size_t)(e0 + e)*240 + 160 + col16*5 + i] = (__bf16)val;
                    else        atomicAdd(agg + srcs[e]*240 + 160 + col16*5 + i, val);
                }
            }
        }
    }
}

// ---------------------------------------------------------------------------
// Node kernel (unchanged from R5)
// ---------------------------------------------------------------------------
__global__ __launch_bounds__(256, 2) void node_kernel(
    const float* __restrict__ nf, const float* __restrict__ mcplg,
    const float* __restrict__ ohg,
    const float* __restrict__ cW1, const float* __restrict__ cb1,
    const float* __restrict__ cW2, const float* __restrict__ cb2,
    const float* __restrict__ gsW, const float* __restrict__ gsb,
    const float* __restrict__ mW1, const float* __restrict__ mb1,
    const float* __restrict__ mW2, const float* __restrict__ mb2,
    const float* __restrict__ lng, const float* __restrict__ lnb,
    const float* __restrict__ rW0, const float* __restrict__ rb0,
    const float* __restrict__ rW1, const float* __restrict__ rW2,
    const float* __restrict__ ohT, float* out0, float* out1)
{
    __shared__ __align__(16) unsigned char pool[68608];
    float* mcp  = (float*)(pool + 0);      // [16][128]
    float* ohv  = (float*)(pool + 8192);   // [16][96]
    float* nsr  = (float*)(pool + 14336);  // [16][240]
    float* anew = (float*)(pool + 29696);  // [16][240]
    float* t12  = (float*)(pool + 45056);  // [16][128]
    float* cfg  = (float*)(pool + 53248);  // [16][112]
    float* scm  = (float*)(pool + 60416);  // [16][128]

    const int t  = threadIdx.x;
    const int g  = t >> 7;
    const int o  = t & 127;
    const int nb = g * 8;
    const int n0 = blockIdx.x * NPB;

    for (int idx = t; idx < NPB * 128; idx += 256) {
        int n = idx >> 7, k = idx & 127;
        mcp[n*128 + k] = mcplg[(n0 + n) * 128 + k];
    }
    for (int idx = t; idx < NPB * 96; idx += 256) {
        int n = idx / 96, k = idx - n * 96;
        ohv[n*96 + k] = (k < 95) ? ohg[(n0 + n) * 95 + k] : 0.f;
    }
    for (int idx = t; idx < NPB * 240; idx += 256) {
        int n = idx / 240, k = idx - n * 240;
        nsr[n*240 + k]  = nf[(n0 + n) * DIM + k];
        anew[n*240 + k] = out0[(n0 + n) * DIM + k];
    }
    __syncthreads();

    {
        float a[8]; float b = cb1[o];
        #pragma unroll
        for (int i = 0; i < 8; i++) a[i] = b;
        #pragma unroll 2
        for (int k4 = 0; k4 < 32; k4++) {
            float w0 = cW1[(4*k4+0)*128 + o], w1 = cW1[(4*k4+1)*128 + o],
                  w2 = cW1[(4*k4+2)*128 + o], w3 = cW1[(4*k4+3)*128 + o];
            #pragma unroll
            for (int i = 0; i < 8; i++) {
                float4 m = *(const float4*)&mcp[(nb+i)*128 + 4*k4];
                a[i] += m.x*w0 + m.y*w1 + m.z*w2 + m.w*w3;
            }
        }
        #pragma unroll
        for (int i = 0; i < 8; i++) { float x = a[i]; t12[(nb+i)*128 + o] = x * sigf(x); }
    }
    __syncthreads();

    if (o < 112) {
        float a[8]; float b = cb2[o];
        #pragma unroll
        for (int i = 0; i < 8; i++) a[i] = b;
        #pragma unroll 2
        for (int k4 = 0; k4 < 32; k4++) {
            float w0 = cW2[(4*k4+0)*112 + o], w1 = cW2[(4*k4+1)*112 + o],
                  w2 = cW2[(4*k4+2)*112 + o], w3 = cW2[(4*k4+3)*112 + o];
            #pragma unroll
            for (int i = 0; i < 8; i++) {
                float4 m = *(const float4*)&t12[(nb+i)*128 + 4*k4];
                a[i] += m.x*w0 + m.y*w1 + m.z*w2 + m.w*w3;
            }
        }
        #pragma unroll
        for (int i = 0; i < 8; i++) cfg[(nb+i)*112 + o] = a[i];
    }
    __syncthreads();

    for (int idx = t; idx < NPB * 240; idx += 256) {
        int n = idx / 240, d = idx - n * 240;
        int ch = (d < 64) ? d : (d < 160 ? 64 + (d - 64) / 3 : 96 + (d - 160) / 5);
        anew[n*240 + d] *= 0.25f * cfg[n*112 + ch];
    }
    __syncthreads();

    {
        float a[8]; float b = gsb[o];
        #pragma unroll
        for (int i = 0; i < 8; i++) a[i] = b;
        #pragma unroll 2
        for (int k4 = 0; k4 < 16; k4++) {
            float w0 = gsW[(4*k4+0)*128 + o], w1 = gsW[(4*k4+1)*128 + o],
                  w2 = gsW[(4*k4+2)*128 + o], w3 = gsW[(4*k4+3)*128 + o];
            #pragma unroll
            for (int i = 0; i < 8; i++) {
                float4 m = *(const float4*)&anew[(nb+i)*240 + 4*k4];
                a[i] += m.x*w0 + m.y*w1 + m.z*w2 + m.w*w3;
            }
        }
        #pragma unroll
        for (int i = 0; i < 8; i++) scm[(nb+i)*128 + o] = a[i];
    }
    __syncthreads();

    {
        float a[8]; float b = mb1[o];
        #pragma unroll
        for (int i = 0; i < 8; i++) a[i] = b;
        #pragma unroll 2
        for (int k4 = 0; k4 < 32; k4++) {
            float w0 = mW1[(4*k4+0)*128 + o], w1 = mW1[(4*k4+1)*128 + o],
                  w2 = mW1[(4*k4+2)*128 + o], w3 = mW1[(4*k4+3)*128 + o];
            #pragma unroll
            for (int i = 0; i < 8; i++) {
                float4 m = *(const float4*)&scm[(nb+i)*128 + 4*k4];
                a[i] += m.x*w0 + m.y*w1 + m.z*w2 + m.w*w3;
            }
        }
        #pragma unroll 2
        for (int k4 = 0; k4 < 32; k4++) {
            float w0 = mW1[(128+4*k4+0)*128 + o], w1 = mW1[(128+4*k4+1)*128 + o],
                  w2 = mW1[(128+4*k4+2)*128 + o], w3 = mW1[(128+4*k4+3)*128 + o];
            #pragma unroll
            for (int i = 0; i < 8; i++) {
                float4 m = *(const float4*)&mcp[(nb+i)*128 + 4*k4];
                a[i] += m.x*w0 + m.y*w1 + m.z*w2 + m.w*w3;
            }
        }
        #pragma unroll
        for (int i = 0; i < 8; i++) { float x = a[i]; t12[(nb+i)*128 + o] = x * sigf(x); }
    }
    __syncthreads();

    {
        float a[8]; float b = mb2[o];
        #pragma unroll
        for (int i = 0; i < 8; i++) a[i] = b;
        #pragma unroll 2
        for (int k4 = 0; k4 < 32; k4++) {
            float w0 = mW2[(4*k4+0)*128 + o], w1 = mW2[(4*k4+1)*128 + o],
                  w2 = mW2[(4*k4+2)*128 + o], w3 = mW2[(4*k4+3)*128 + o];
            #pragma unroll
            for (int i = 0; i < 8; i++) {
                float4 m = *(const float4*)&t12[(nb+i)*128 + 4*k4];
                a[i] += m.x*w0 + m.y*w1 + m.z*w2 + m.w*w3;
            }
        }
        #pragma unroll
        for (int i = 0; i < 8; i++) scm[(nb+i)*128 + o] = mcp[(nb+i)*128 + o] + a[i];
    }
    __syncthreads();

    {
        int n = t >> 4, l = t & 15;
        float x[8]; float s = 0.f, ss = 0.f;
        #pragma unroll
        for (int i = 0; i < 8; i++) { x[i] = scm[n*128 + l + 16*i]; s += x[i]; ss += x[i]*x[i]; }
        #pragma unroll
        for (int off = 8; off > 0; off >>= 1) {
            s  += __shfl_down(s,  off, 16);
            ss += __shfl_down(ss, off, 16);
        }
        s  = __shfl(s, 0, 16);
        ss = __shfl(ss, 0, 16);
        float mu   = s * (1.f / 128.f);
        float var  = ss * (1.f / 128.f) - mu * mu;
        float rstd = rsqrtf(var + 1e-5f);
        float* op = out1 + (n0 + n) * 128;
        #pragma unroll
        for (int i = 0; i < 8; i++) {
            int c = l + 16*i;
            op[c] = (x[i] - mu) * rstd * lng[c] + lnb[c];
        }
    }

    if (o < 112) {
        float a[8] = {0.f,0.f,0.f,0.f,0.f,0.f,0.f,0.f};
        #pragma unroll 2
        for (int k4 = 0; k4 < 24; k4++) {
            float w0 = ohT[(4*k4+0)*112 + o], w1 = ohT[(4*k4+1)*112 + o],
                  w2 = ohT[(4*k4+2)*112 + o], w3 = ohT[(4*k4+3)*112 + o];
            #pragma unroll
            for (int i = 0; i < 8; i++) {
                float4 m = *(const float4*)&ohv[(nb+i)*96 + 4*k4];
                a[i] += m.x*w0 + m.y*w1 + m.z*w2 + m.w*w3;
            }
        }
        #pragma unroll
        for (int i = 0; i < 8; i++) cfg[(nb+i)*112 + o] = a[i];
    }
    __syncthreads();

    const float c_new = 0.4472135955f;
    const float c_old = 0.8944271910f;
    for (int idx = t; idx < NPB * 240; idx += 256) {
        int n = idx / 240, d = idx - n * 240;
        float res, gg;
        if (d < 64) {
            float acc = rb0[d];
            #pragma unroll 4
            for (int c = 0; c < 64; c++) acc += nsr[n*240 + c] * rW0[c * 64 + d];
            res = acc; gg = cfg[n*112 + d];
        } else if (d < 160) {
            int dd = d - 64, oo = dd / 3, j = dd - oo * 3;
            float acc = 0.f;
            #pragma unroll 4
            for (int c = 0; c < 32; c++) acc += nsr[n*240 + 64 + c*3 + j] * rW1[c * 32 + oo];
            res = acc; gg = cfg[n*112 + 64 + oo];
        } else {
            int dd = d - 160, oo = dd / 5, j = dd - oo * 5;
            float acc = 0.f;
            #pragma unroll 4
            for (int c = 0; c < 16; c++) acc += nsr[n*240 + 160 + c*5 + j] * rW2[c * 16 + oo];
            res = acc; gg = cfg[n*112 + 96 + oo];
        }
        float v = c_new * anew[n*240 + d] + c_old * res;
        out0[(n0 + n) * DIM + d] = v * (1.f + gg);
    }
}

extern "C" void kernel_launch(void* const* d_in, const int* in_sizes, int n_in,
                              void* d_out, int out_size, void* d_ws, size_t ws_size,
                              hipStream_t stream) {
    const float* nf      = (const float*)d_in[0];
    const float* ef      = (const float*)d_in[1];
    const float* lat     = (const float*)d_in[2];
    const float* mcpl    = (const float*)d_in[3];
    const float* ohot    = (const float*)d_in[4];
    const float* D1      = (const float*)d_in[5];
    const float* D2      = (const float*)d_in[6];
    const float* so2_W0  = (const float*)d_in[7];
    const float* so2_W1  = (const float*)d_in[8];
    const float* so2_W2  = (const float*)d_in[9];
    const float* so2_Ws  = (const float*)d_in[10];
    const float* env_W   = (const float*)d_in[11];
    const float* post_W0 = (const float*)d_in[12];
    const float* post_b0 = (const float*)d_in[13];
    const float* post_W1 = (const float*)d_in[14];
    const float* post_W2 = (const float*)d_in[15];
    const float* res_W0  = (const float*)d_in[16];
    const float* res_b0  = (const float*)d_in[17];
    const float* res_W1  = (const float*)d_in[18];
    const float* res_W2  = (const float*)d_in[19];
    const float* cpl_W1  = (const float*)d_in[20];
    const float* cpl_b1  = (const float*)d_in[21];
    const float* cpl_W2  = (const float*)d_in[22];
    const float* cpl_b2  = (const float*)d_in[23];
    const float* gs_W    = (const float*)d_in[24];
    const float* gs_b    = (const float*)d_in[25];
    const float* msg_W1  = (const float*)d_in[26];
    const float* msg_b1  = (const float*)d_in[27];
    const float* msg_W2  = (const float*)d_in[28];
    const float* msg_b2  = (const float*)d_in[29];
    const float* ln_g    = (const float*)d_in[30];
    const float* ln_b    = (const float*)d_in[31];
    const float* oh_w0   = (const float*)d_in[32];
    const float* oh_w1   = (const float*)d_in[33];
    const float* oh_w2   = (const float*)d_in[34];
    const int*   eidx    = (const int*)d_in[35];   // (2,E); row 0 = src

    float* out0 = (float*)d_out;                     // N*DIM, doubles as agg
    float* out1 = (float*)d_out + (size_t)NN * DIM;  // N*CPL
    char*   wsB = (char*)d_ws;
    __bf16* wsb = (__bf16*)d_ws;
    float*  ohT = (float*)(wsB + OHT_BYTE_OFF);

    const size_t need = (size_t)MSG_BYTE_OFF + (size_t)NE * 240 * 2;
    const bool planA = ws_size >= need;

    (void)hipMemsetAsync(out0, 0, (size_t)NN * DIM * sizeof(float), stream);

    prep_kernel<<<56, 256, 0, stream>>>(so2_Ws, env_W, so2_W0, so2_W1, so2_W2,
                                        post_W0, post_W1, post_W2,
                                        oh_w0, oh_w1, oh_w2, wsb, ohT);

    if (planA) {
        int*    cnt  = (int*)(wsB + CNT_BYTE_OFF);
        int*    row  = (int*)(wsB + ROW_BYTE_OFF);
        int*    cur  = (int*)(wsB + CUR_BYTE_OFF);
        int*    eidl = (int*)(wsB + EID_BYTE_OFF);
        __bf16* msg  = (__bf16*)(wsB + MSG_BYTE_OFF);

        (void)hipMemsetAsync(cnt, 0, 10240 * sizeof(int), stream);
        count_kernel<<<(NE + 255) / 256, 256, 0, stream>>>(eidx, cnt);
        scan_kernel<<<1, 256, 0, stream>>>(cnt, row, cur);
        fill_kernel<<<(NE + 255) / 256, 256, 0, stream>>>(eidx, cur, eidl);

        edge_mfma_kernel<<<NE / EB, 256, 0, stream>>>(
            nf, ef, lat, D1, D2, post_b0, eidx, wsb, out0, msg);

        agg_kernel<<<(NN + 3) / 4, 256, 0, stream>>>(msg, row, eidl, out0);
    } else {
        edge_mfma_kernel<<<NE / EB, 256, 0, stream>>>(
            nf, ef, lat, D1, D2, post_b0, eidx, wsb, out0, nullptr);
    }

    node_kernel<<<NN / NPB, 256, 0, stream>>>(
        nf, mcpl, ohot, cpl_W1, cpl_b1, cpl_W2, cpl_b2, gs_W, gs_b,
        msg_W1, msg_b1, msg_W2, msg_b2, ln_g, ln_b,
        res_W0, res_b0, res_W1, res_W2, ohT, out0, out1);
}